// Round 4
// baseline (562.724 us; speedup 1.0000x reference)
//
#include <hip/hip_runtime.h>
#include <hip/hip_cooperative_groups.h>
#include <stdint.h>

namespace cg = cooperative_groups;

#define NDIM  256   // accumulator width
#define NFEAT 640   // piece features per sample
#define NROWS 641   // 640 features + 1 king bias row
#define SG    8     // slots per group
#define GRP   8     // groups per king (pass loop covers overflow)
#define RP    4     // row parts (160 rows each)
#define VGRID 2048  // virtual grid: 64 kings * GRP * RP
#define MAXLIST 512

typedef unsigned short ushort4v __attribute__((ext_vector_type(4)));
typedef unsigned short ushort8v __attribute__((ext_vector_type(8)));

// ---- LDS layouts (overlaid on one char array) ----
struct GaLds {                        // gather phase: 19092 B -> 8 blocks/CU
    unsigned red[4][SG][NDIM / 2];    // 16 KB packed u16 per-wave partials (16B-aligned first)
    unsigned mask[160];               // per-row activity bits
    int list[MAXLIST];                // this king's slot ids, index order (deterministic)
    int wcnt[4];
    int cnt;
    int samp[SG];
};
struct CbLds {                        // combine phase: 1312 B
    int8_t x[NDIM];
    int fc[256];
    int8_t x2[32];
};
#define SMEM_BYTES (sizeof(GaLds) > sizeof(CbLds) ? sizeof(GaLds) : sizeof(CbLds))

// ============================ gather one virtual block ============================
template<bool RAWW, bool RAWPP>
__device__ __forceinline__ void gather_vb(
    int vb, bool first, const void* __restrict__ ppv, const int* __restrict__ kp,
    const void* __restrict__ Wv, unsigned short* __restrict__ partial,
    int nslots, GaLds* sh)
{
    const int t = threadIdx.x, l = t & 63, g = t >> 6;
    const int k = vb & 63;             // king (vb%64 stable across grid-stride since grid%64==0)
    const int rest = vb >> 6;
    const int p = rest & (RP - 1);     // row part
    const int gi = rest / RP;          // slot group

    if (first) {
        // ---- deterministic index-ordered compaction of king k's slots ----
        if (t == 0) sh->cnt = 0;
        __syncthreads();
        for (int c0 = 0; c0 < nslots; c0 += 256) {
            const int s = c0 + t;
            const bool f = (s < nslots) && (kp[s] == k);
            const unsigned long long m = __ballot(f);
            if (l == 0) sh->wcnt[g] = (int)__popcll(m);
            __syncthreads();
            int base = sh->cnt;
            for (int w = 0; w < g; ++w) base += sh->wcnt[w];
            const int pos = base + (int)__popcll(m & ((1ull << l) - 1ull));
            if (f && pos < MAXLIST) sh->list[pos] = s;
            __syncthreads();
            if (t == 0) sh->cnt += sh->wcnt[0] + sh->wcnt[1] + sh->wcnt[2] + sh->wcnt[3];
            __syncthreads();
        }
    }
    const int cnt = min(sh->cnt, MAXLIST);
    const int r0 = p * 160;
    const char* Wk = (const char*)Wv + (size_t)k * NROWS * NDIM * (RAWW ? 2 : 4);

    for (int lbase = gi * SG; lbase < cnt; lbase += GRP * SG) {
        const int ns = min(SG, cnt - lbase);
        const unsigned emask = (1u << ns) - 1u;
        if (t < SG) sh->samp[t] = sh->list[lbase + min(t, ns - 1)] >> 1;
        __syncthreads();

        // ---- per-row activity masks for rows [r0, r0+160) ----
        for (int r = t; r < 160; r += 256) {
            unsigned mm = 0;
            #pragma unroll
            for (int i = 0; i < SG; ++i) {
                const int s = sh->samp[i];
                int v;
                if (RAWPP) v = ((const uint8_t*)ppv)[(size_t)s * NFEAT + r0 + r];
                else       v = ((const int*)ppv)[(size_t)s * NFEAT + r0 + r];
                mm |= (v != 0 ? 1u : 0u) << i;
            }
            sh->mask[r] = mm & emask;
        }
        __syncthreads();

        // ---- row loop: one row load, packed-u16 adds (mod 2^16 exact) ----
        ushort4v acc[SG];
        #pragma unroll
        for (int i = 0; i < SG; ++i) acc[i] = (ushort4v)0;

        #pragma unroll 2
        for (int rr = 0; rr < 40; ++rr) {
            const int lr = g * 40 + rr;
            unsigned mm = sh->mask[lr];
            mm = __builtin_amdgcn_readfirstlane(mm);
            ushort4v w;
            if (RAWW) {
                w = *(const ushort4v*)(Wk + (size_t)(r0 + lr) * 512 + (size_t)l * 8);
            } else {
                const int4 u = *(const int4*)(Wk + (size_t)(r0 + lr) * 1024 + (size_t)l * 16);
                w.x = (unsigned short)u.x; w.y = (unsigned short)u.y;
                w.z = (unsigned short)u.z; w.w = (unsigned short)u.w;
            }
            #pragma unroll
            for (int i = 0; i < SG; ++i)
                if (mm & (1u << i)) acc[i] += w;
        }

        // ---- cross-wave reduce, write u16 partials indexed by SLOT id ----
        #pragma unroll
        for (int i = 0; i < SG; ++i)
            *(ushort4v*)&sh->red[g][i][2 * l] = acc[i];
        __syncthreads();

        const int i = t >> 5;
        const int j4 = (t & 31) * 4;
        if (i < ns) {
            ushort8v s8 = *(const ushort8v*)&sh->red[0][i][j4];
            #pragma unroll
            for (int g2 = 1; g2 < 4; ++g2) s8 += *(const ushort8v*)&sh->red[g2][i][j4];
            const int slot = sh->list[lbase + i];
            *(ushort8v*)&partial[((size_t)p * nslots + slot) * NDIM + (size_t)(t & 31) * 8] = s8;
        }
        __syncthreads();   // protect samp/mask/red before next pass
    }
}

// ============================ combine one sample ============================
template<bool RAWW>
__device__ __forceinline__ void combine_one(
    int b, const unsigned short* __restrict__ partial, const int* __restrict__ kp,
    const void* __restrict__ Wv, const void* __restrict__ ibv,
    const void* __restrict__ w1v, const int* __restrict__ b1,
    const void* __restrict__ w2v, const int* __restrict__ b2,
    const void* __restrict__ owv, int* __restrict__ ws, int nslots, CbLds* sh)
{
    const int t = threadIdx.x;
    const int k0 = kp[2 * b + 0];
    const int k1 = kp[2 * b + 1];
    {
        unsigned tot = 0;  // u16 arithmetic in u32; truncate at end
        #pragma unroll
        for (int pi = 0; pi < RP; ++pi) {
            tot += partial[((size_t)pi * nslots + 2 * b + 0) * NDIM + t];
            tot += partial[((size_t)pi * nslots + 2 * b + 1) * NDIM + t];
        }
        if (RAWW) {
            const uint16_t* Wq = (const uint16_t*)Wv;
            tot += Wq[((size_t)k0 * NROWS + NFEAT) * NDIM + t];
            tot += Wq[((size_t)k1 * NROWS + NFEAT) * NDIM + t];
            tot += ((const uint16_t*)ibv)[t];
        } else {
            const int* Wq = (const int*)Wv;
            tot += (unsigned)Wq[((size_t)k0 * NROWS + NFEAT) * NDIM + t];
            tot += (unsigned)Wq[((size_t)k1 * NROWS + NFEAT) * NDIM + t];
            tot += (unsigned)((const int*)ibv)[t];
        }
        int v = (int)(int16_t)(uint16_t)tot;   // int16 wraparound semantics
        v = v < 0 ? 0 : (v > 127 ? 127 : v);
        sh->x[t] = (int8_t)v;
    }
    __syncthreads();

    // ---- FC1: 32 outputs over concat([x,x]) = fold the two 256-halves of w1 ----
    {
        const int o = t >> 3, part = t & 7;
        int y = 0;
        const uint32_t* xw = (const uint32_t*)sh->x;
        if (RAWW) {
            const uint32_t* w1r = (const uint32_t*)((const char*)w1v + o * 512);
            #pragma unroll
            for (int i = 0; i < 8; ++i) {
                const int wi = part * 8 + i;
                const uint32_t xv = xw[wi];
                const uint32_t wa = w1r[wi];
                const uint32_t wb = w1r[64 + wi];
                #pragma unroll
                for (int jj = 0; jj < 4; ++jj) {
                    const int xj  = (int)((xv >> (8 * jj)) & 0xFFu);
                    const int waj = (int)(int8_t)(uint8_t)(wa >> (8 * jj));
                    const int wbj = (int)(int8_t)(uint8_t)(wb >> (8 * jj));
                    y += xj * (waj + wbj);
                }
            }
        } else {
            const int* w1r = (const int*)w1v + o * 512;
            #pragma unroll
            for (int i = 0; i < 8; ++i) {
                const int wi = part * 8 + i;
                const uint32_t xv = xw[wi];
                #pragma unroll
                for (int jj = 0; jj < 4; ++jj) {
                    const int xj = (int)((xv >> (8 * jj)) & 0xFFu);
                    y += xj * (w1r[wi * 4 + jj] + w1r[256 + wi * 4 + jj]);
                }
            }
        }
        sh->fc[t] = y;
    }
    __syncthreads();

    if (t < 32) {
        int y = b1[t];
        #pragma unroll
        for (int pq = 0; pq < 8; ++pq) y += sh->fc[t * 8 + pq];
        y >>= 6;                                  // floor_divide(y, 64)
        y = y < 0 ? 0 : (y > 127 ? 127 : y);
        sh->x2[t] = (int8_t)y;
    }
    __syncthreads();

    if (t < 32) {
        int y = b2[t];
        const uint32_t* x2w = (const uint32_t*)sh->x2;
        if (RAWW) {
            const uint32_t* w2r = (const uint32_t*)((const char*)w2v + t * 32);
            #pragma unroll
            for (int i = 0; i < 8; ++i) {
                const uint32_t xv = x2w[i];
                const uint32_t wv = w2r[i];
                #pragma unroll
                for (int jj = 0; jj < 4; ++jj)
                    y += (int)((xv >> (8 * jj)) & 0xFFu) * (int)(int8_t)(uint8_t)(wv >> (8 * jj));
            }
        } else {
            const int* w2r = (const int*)w2v + t * 32;
            #pragma unroll
            for (int i = 0; i < 8; ++i) {
                const uint32_t xv = x2w[i];
                #pragma unroll
                for (int jj = 0; jj < 4; ++jj)
                    y += (int)((xv >> (8 * jj)) & 0xFFu) * w2r[i * 4 + jj];
            }
        }
        y >>= 6;
        y = y < 0 ? 0 : (y > 127 ? 127 : y);
        const int owx = RAWW ? (int)((const int8_t*)owv)[t] : ((const int*)owv)[t];
        int pr = y * owx;
        #pragma unroll
        for (int off = 16; off > 0; off >>= 1) pr += __shfl_down(pr, off, 32);
        if (t == 0) atomicAdd(ws, pr);
    }
    __syncthreads();   // protect sh before next grid-stride iteration
}

// ============================ the single cooperative kernel ============================
template<bool RAWW, bool RAWPP>
__device__ __forceinline__ void run_all(
    cg::grid_group& grid, char* smem,
    const void* pp, const int* kp, const void* W, const void* ib,
    const void* w1, const int* b1, const void* w2, const int* b2,
    const void* ow, const int* ob, int* out, int* ws,
    unsigned short* partial, int nslots)
{
    GaLds* ga = (GaLds*)smem;
    CbLds* cb = (CbLds*)smem;

    // ---- gather phase over virtual blocks (grid.x % 64 == 0 keeps king constant) ----
    bool first = true;
    for (int vb = blockIdx.x; vb < VGRID; vb += gridDim.x) {
        gather_vb<RAWW, RAWPP>(vb, first, pp, kp, W, partial, nslots, ga);
        first = false;
    }
    __threadfence();
    grid.sync();

    // ---- combine phase ----
    const int nsamp = nslots >> 1;
    for (int b = blockIdx.x; b < nsamp; b += gridDim.x)
        combine_one<RAWW>(b, partial, kp, W, ib, w1, b1, w2, b2, ow, ws, nslots, cb);
    __threadfence();
    grid.sync();

    // ---- finalize ----
    if (blockIdx.x == 0 && threadIdx.x == 0) {
        const int s = __hip_atomic_load(ws, __ATOMIC_RELAXED, __HIP_MEMORY_SCOPE_AGENT);
        out[0] = (s + ob[0]) >> 4;   // floor_divide(s, 16)
    }
}

__global__ __launch_bounds__(256, 8) void nnue_coop(
    const void* pp, const int* kp, const void* W, const void* ib,
    const void* w1, const int* b1, const void* w2, const int* b2,
    const void* ow, const int* ob, int* out, int* ws,
    unsigned short* partial, int nslots)
{
    cg::grid_group grid = cg::this_grid();
    __shared__ __align__(16) char smem[SMEM_BYTES];
    __shared__ int s_flags;

    if (threadIdx.x == 0) {
        int raww = 0, rawpp = 0;
        const int* W32 = (const int*)W;
        const int* pp32 = (const int*)pp;
        for (int i = 0; i < 16; ++i) {
            const int v = W32[i];                     // int32 layout => |v| <= 32767
            if (v > 32767 || v < -32768) raww = 1;    // packed int16 pairs look huge
            const int u = pp32[i];                    // int32 layout => {0,1}
            if (u != 0 && u != 1) rawpp = 1;          // packed bool bytes exceed 1
        }
        s_flags = raww | (rawpp << 1);
        if (blockIdx.x == 0)
            __hip_atomic_store(ws, 0, __ATOMIC_RELAXED, __HIP_MEMORY_SCOPE_AGENT);
    }
    __syncthreads();
    const int raww = s_flags & 1, rawpp = (s_flags >> 1) & 1;  // grid-uniform

    if (raww) {
        if (rawpp) run_all<true,  true >(grid, smem, pp, kp, W, ib, w1, b1, w2, b2, ow, ob, out, ws, partial, nslots);
        else       run_all<true,  false>(grid, smem, pp, kp, W, ib, w1, b1, w2, b2, ow, ob, out, ws, partial, nslots);
    } else {
        if (rawpp) run_all<false, true >(grid, smem, pp, kp, W, ib, w1, b1, w2, b2, ow, ob, out, ws, partial, nslots);
        else       run_all<false, false>(grid, smem, pp, kp, W, ib, w1, b1, w2, b2, ow, ob, out, ws, partial, nslots);
    }
}

// ============================ fallback (round-1 monolithic) ============================
struct SharedBuf {
    uint8_t pp[NFEAT];
    int     acc[4][NDIM];
    alignas(16) int8_t x[NDIM];
    int     fc[256];
    alignas(4) int8_t x2[32];
    int     list[4][160];
};

__global__ void detect_layout(const int* __restrict__ W32, const int* __restrict__ pp32,
                              int* __restrict__ ws) {
    int raww = 0, rawpp = 0;
    for (int i = 0; i < 16; ++i) {
        const int v = W32[i];
        if (v > 32767 || v < -32768) raww = 1;
        const int u = pp32[i];
        if (u != 0 && u != 1) rawpp = 1;
    }
    ws[0] = 0; ws[1] = raww; ws[2] = rawpp;
}

template<bool RAWW, bool RAWPP>
__device__ __forceinline__ void mono_body(
    const void* __restrict__ ppv, const int* __restrict__ kp,
    const void* __restrict__ Wv,  const void* __restrict__ ibv,
    const void* __restrict__ w1v, const int* __restrict__ b1,
    const void* __restrict__ w2v, const int* __restrict__ b2,
    const void* __restrict__ owv, int* __restrict__ ws, SharedBuf& sh)
{
    const int b = blockIdx.x;
    const int t = threadIdx.x;
    const int l = t & 63;
    const int g = t >> 6;

    if (RAWPP) {
        const uint32_t* src = (const uint32_t*)((const uint8_t*)ppv + (size_t)b * NFEAT);
        if (t < NFEAT / 4) ((uint32_t*)sh.pp)[t] = src[t];
    } else {
        const int* src = (const int*)ppv + (size_t)b * NFEAT;
        for (int i = t; i < NFEAT; i += 256) sh.pp[i] = (uint8_t)(src[i] != 0);
    }
    __syncthreads();

    const int base = g * 160;
    int cnt = 0;
    for (int c = 0; c < 160; c += 64) {
        const int idx = c + l;
        const bool flag = (idx < 160) && (sh.pp[base + idx] != 0);
        const unsigned long long mmask = __ballot(flag);
        const int pos = cnt + (int)__popcll(mmask & ((1ull << l) - 1ull));
        if (flag) sh.list[g][pos] = base + idx;
        cnt += (int)__popcll(mmask);
    }

    const int k0 = kp[b * 2 + 0];
    const int k1 = kp[b * 2 + 1];
    int a0 = 0, a1 = 0, a2 = 0, a3 = 0, a4 = 0, a5 = 0, a6 = 0, a7 = 0;

    if (RAWW) {
        const char* W0 = (const char*)Wv + (size_t)k0 * (NROWS * NDIM * 2);
        const char* W1 = (const char*)Wv + (size_t)k1 * (NROWS * NDIM * 2);
        const int lo = l * 8;
        auto step = [&](int f) {
            const uint2 u0 = *(const uint2*)(W0 + f * 512 + lo);
            const uint2 u1 = *(const uint2*)(W1 + f * 512 + lo);
            a0 += (int)(u0.x & 0xFFFFu); a1 += (int)(u0.x >> 16);
            a2 += (int)(u0.y & 0xFFFFu); a3 += (int)(u0.y >> 16);
            a4 += (int)(u1.x & 0xFFFFu); a5 += (int)(u1.x >> 16);
            a6 += (int)(u1.y & 0xFFFFu); a7 += (int)(u1.y >> 16);
        };
        int j = 0;
        for (; j + 4 <= cnt; j += 4) {
            const int f0 = sh.list[g][j], f1 = sh.list[g][j + 1];
            const int f2 = sh.list[g][j + 2], f3 = sh.list[g][j + 3];
            step(f0); step(f1); step(f2); step(f3);
        }
        for (; j < cnt; ++j) step(sh.list[g][j]);
    } else {
        const char* W0 = (const char*)Wv + (size_t)k0 * (NROWS * NDIM * 4);
        const char* W1 = (const char*)Wv + (size_t)k1 * (NROWS * NDIM * 4);
        const int lo = l * 16;
        auto step = [&](int f) {
            const int4 u0 = *(const int4*)(W0 + f * 1024 + lo);
            const int4 u1 = *(const int4*)(W1 + f * 1024 + lo);
            a0 += u0.x; a1 += u0.y; a2 += u0.z; a3 += u0.w;
            a4 += u1.x; a5 += u1.y; a6 += u1.z; a7 += u1.w;
        };
        int j = 0;
        for (; j + 4 <= cnt; j += 4) {
            const int f0 = sh.list[g][j], f1 = sh.list[g][j + 1];
            const int f2 = sh.list[g][j + 2], f3 = sh.list[g][j + 3];
            step(f0); step(f1); step(f2); step(f3);
        }
        for (; j < cnt; ++j) step(sh.list[g][j]);
    }

    sh.acc[g][4 * l + 0] = a0 + a4;
    sh.acc[g][4 * l + 1] = a1 + a5;
    sh.acc[g][4 * l + 2] = a2 + a6;
    sh.acc[g][4 * l + 3] = a3 + a7;
    __syncthreads();

    {
        const int d = t;
        int tot = sh.acc[0][d] + sh.acc[1][d] + sh.acc[2][d] + sh.acc[3][d];
        int kb0, kb1, ibx;
        if (RAWW) {
            const int16_t* Wq = (const int16_t*)Wv;
            kb0 = Wq[((size_t)k0 * NROWS + NFEAT) * NDIM + d];
            kb1 = Wq[((size_t)k1 * NROWS + NFEAT) * NDIM + d];
            ibx = ((const int16_t*)ibv)[d];
        } else {
            const int* Wq = (const int*)Wv;
            kb0 = Wq[((size_t)k0 * NROWS + NFEAT) * NDIM + d];
            kb1 = Wq[((size_t)k1 * NROWS + NFEAT) * NDIM + d];
            ibx = ((const int*)ibv)[d];
        }
        tot += kb0 + kb1 + ibx;
        int v = (int)(int16_t)(uint16_t)(uint32_t)tot;
        v = v < 0 ? 0 : (v > 127 ? 127 : v);
        sh.x[d] = (int8_t)v;
    }
    __syncthreads();

    {
        const int o = t >> 3, part = t & 7;
        int y = 0;
        const uint32_t* xw = (const uint32_t*)sh.x;
        if (RAWW) {
            const uint32_t* w1r = (const uint32_t*)((const char*)w1v + o * 512);
            #pragma unroll
            for (int i = 0; i < 8; ++i) {
                const int wi = part * 8 + i;
                const uint32_t xv = xw[wi];
                const uint32_t wa = w1r[wi];
                const uint32_t wb = w1r[64 + wi];
                #pragma unroll
                for (int jj = 0; jj < 4; ++jj) {
                    const int xj  = (int)((xv >> (8 * jj)) & 0xFFu);
                    const int waj = (int)(int8_t)(uint8_t)(wa >> (8 * jj));
                    const int wbj = (int)(int8_t)(uint8_t)(wb >> (8 * jj));
                    y += xj * (waj + wbj);
                }
            }
        } else {
            const int* w1r = (const int*)w1v + o * 512;
            #pragma unroll
            for (int i = 0; i < 8; ++i) {
                const int wi = part * 8 + i;
                const uint32_t xv = xw[wi];
                #pragma unroll
                for (int jj = 0; jj < 4; ++jj) {
                    const int xj = (int)((xv >> (8 * jj)) & 0xFFu);
                    y += xj * (w1r[wi * 4 + jj] + w1r[256 + wi * 4 + jj]);
                }
            }
        }
        sh.fc[t] = y;
    }
    __syncthreads();

    if (t < 32) {
        int y = b1[t];
        #pragma unroll
        for (int pq = 0; pq < 8; ++pq) y += sh.fc[t * 8 + pq];
        y >>= 6;
        y = y < 0 ? 0 : (y > 127 ? 127 : y);
        sh.x2[t] = (int8_t)y;
    }
    __syncthreads();

    if (t < 32) {
        int y = b2[t];
        const uint32_t* x2w = (const uint32_t*)sh.x2;
        if (RAWW) {
            const uint32_t* w2r = (const uint32_t*)((const char*)w2v + t * 32);
            #pragma unroll
            for (int i = 0; i < 8; ++i) {
                const uint32_t xv = x2w[i];
                const uint32_t wv = w2r[i];
                #pragma unroll
                for (int jj = 0; jj < 4; ++jj)
                    y += (int)((xv >> (8 * jj)) & 0xFFu) * (int)(int8_t)(uint8_t)(wv >> (8 * jj));
            }
        } else {
            const int* w2r = (const int*)w2v + t * 32;
            #pragma unroll
            for (int i = 0; i < 8; ++i) {
                const uint32_t xv = x2w[i];
                #pragma unroll
                for (int jj = 0; jj < 4; ++jj)
                    y += (int)((xv >> (8 * jj)) & 0xFFu) * w2r[i * 4 + jj];
            }
        }
        y >>= 6;
        y = y < 0 ? 0 : (y > 127 ? 127 : y);
        const int owx = RAWW ? (int)((const int8_t*)owv)[t] : ((const int*)owv)[t];
        int pr = y * owx;
        #pragma unroll
        for (int off = 16; off > 0; off >>= 1) pr += __shfl_down(pr, off, 32);
        if (t == 0) atomicAdd(ws, pr);
    }
}

__global__ __launch_bounds__(256, 4) void nnue_mono(
    const void* __restrict__ pp, const int* __restrict__ kp,
    const void* __restrict__ W,  const void* __restrict__ ib,
    const void* __restrict__ w1, const int* __restrict__ b1,
    const void* __restrict__ w2, const int* __restrict__ b2,
    const void* __restrict__ ow, int* __restrict__ ws)
{
    __shared__ SharedBuf sh;
    const int raww = ws[1], rawpp = ws[2];
    if (raww) {
        if (rawpp) mono_body<true,  true >(pp, kp, W, ib, w1, b1, w2, b2, ow, ws, sh);
        else       mono_body<true,  false>(pp, kp, W, ib, w1, b1, w2, b2, ow, ws, sh);
    } else {
        if (rawpp) mono_body<false, true >(pp, kp, W, ib, w1, b1, w2, b2, ow, ws, sh);
        else       mono_body<false, false>(pp, kp, W, ib, w1, b1, w2, b2, ow, ws, sh);
    }
}

__global__ void nnue_finalize(const int* __restrict__ ws, const int* __restrict__ ob,
                              int* __restrict__ out) {
    out[0] = (ws[0] + ob[0]) >> 4;
}

// ============================ host launch ============================
extern "C" void kernel_launch(void* const* d_in, const int* in_sizes, int n_in,
                              void* d_out, int out_size, void* d_ws, size_t ws_size,
                              hipStream_t stream)
{
    const void* pp = d_in[0];
    const int*  kp = (const int*)d_in[1];
    const void* W  = d_in[2];
    const void* ib = d_in[3];
    const void* w1 = d_in[4];
    const int*  b1 = (const int*)d_in[5];
    const void* w2 = d_in[6];
    const int*  b2 = (const int*)d_in[7];
    const void* ow = d_in[8];
    const int*  ob = (const int*)d_in[9];
    int* ws  = (int*)d_ws;
    int* out = (int*)d_out;

    int nslots = 2 * (in_sizes[1] / 2);   // king_positions is (B, 2)

    // ws layout: [0] scalar sum, [1..2] spare, u16 partial at +64 ints
    unsigned short* partial = (unsigned short*)(ws + 64);
    const size_t need = 64 * 4 + (size_t)RP * nslots * NDIM * 2;

    int cus = 0, maxb = 0;
    (void)hipDeviceGetAttribute(&cus, hipDeviceAttributeMultiprocessorCount, 0);
    (void)hipOccupancyMaxActiveBlocksPerMultiprocessor(&maxb, (const void*)nnue_coop, 256, 0);
    int grid = 0;
    if (cus > 0 && maxb > 0) {
        grid = maxb * cus;
        if (grid > VGRID) grid = VGRID;
        grid &= ~63;                       // multiple of 64: king constant per block
    }

    if (ws_size >= need && grid >= 64) {
        void* args[] = { (void*)&pp, (void*)&kp, (void*)&W, (void*)&ib,
                         (void*)&w1, (void*)&b1, (void*)&w2, (void*)&b2,
                         (void*)&ow, (void*)&ob, (void*)&out, (void*)&ws,
                         (void*)&partial, (void*)&nslots };
        hipLaunchCooperativeKernel((const void*)nnue_coop, dim3(grid), dim3(256),
                                   args, 0, stream);
    } else {
        const int B = nslots / 2;
        hipLaunchKernelGGL(detect_layout, dim3(1), dim3(1), 0, stream,
                           (const int*)W, (const int*)pp, ws);
        hipLaunchKernelGGL(nnue_mono, dim3(B), dim3(256), 0, stream,
                           pp, kp, W, ib, w1, b1, w2, b2, ow, ws);
        hipLaunchKernelGGL(nnue_finalize, dim3(1), dim3(1), 0, stream, ws, ob, out);
    }
}

// Round 5
// 166.792 us; speedup vs baseline: 3.3738x; 3.3738x over previous
//
#include <hip/hip_runtime.h>
#include <stdint.h>

#define NDIM  256   // accumulator width
#define NFEAT 640   // piece features per sample
#define NROWS 641   // 640 features + 1 king bias row
#define SG    16    // slots per group
#define MAXG  4     // slot-group blocks per (king, row-block); stride loop covers overflow
#define RB    2     // row-blocks (320 rows each); PARTS = RB*4 waves = 8
#define PARTS 8

typedef unsigned short ushort4v __attribute__((ext_vector_type(4)));

// ============================ bucket + detect ============================
// ws[0]=scalar sum, ws[1]=raw-int16 weights, ws[2]=raw-bool pp, ws[3]=done counter
__global__ void nnue_bucket(const int* __restrict__ kp, const int* __restrict__ W32,
                            const int* __restrict__ pp32, int nslots,
                            int* __restrict__ ws,
                            int* __restrict__ king_start, int* __restrict__ slot_list)
{
    __shared__ int cnt[64];
    __shared__ int off[64];
    const int t = threadIdx.x;
    if (t < 64) cnt[t] = 0;
    if (t == 0) {
        int raww = 0, rawpp = 0;
        for (int i = 0; i < 16; ++i) {
            const int v = W32[i];                     // int32 layout => |v| <= 32767
            if (v > 32767 || v < -32768) raww = 1;    // packed int16 pairs look huge
            const int u = pp32[i];                    // int32 layout => {0,1}
            if (u != 0 && u != 1) rawpp = 1;          // packed bool bytes exceed 1
        }
        ws[0] = 0; ws[1] = raww; ws[2] = rawpp; ws[3] = 0;
    }
    __syncthreads();
    for (int s = t; s < nslots; s += 256) atomicAdd(&cnt[kp[s]], 1);
    __syncthreads();
    if (t == 0) {
        int run = 0;
        for (int k = 0; k < 64; ++k) { off[k] = run; king_start[k] = run; run += cnt[k]; }
        king_start[64] = run;
    }
    __syncthreads();
    for (int s = t; s < nslots; s += 256) {
        const int k = kp[s];
        const int pos = atomicAdd(&off[k], 1);
        slot_list[pos] = s;        // s = 2*sample + side; partial indexed by slot id directly
    }
}

// ============================ king-major gather ============================
struct GaLds {
    unsigned pps[SG][80];   // staged pp bytes: sample i, rows r0..r0+319 (byte per row)
    unsigned mask[320];     // 16-bit activity mask per row
    int sslot[SG];          // slot ids
    int ssamp[SG];          // sample ids
};

template<bool RAWW, bool RAWPP>
__device__ __forceinline__ void gather_body(
    const void* __restrict__ ppv, const void* __restrict__ Wv,
    const int* __restrict__ king_start, const int* __restrict__ slot_list,
    unsigned short* __restrict__ partial, int nslots, GaLds* sh)
{
    const int bid = blockIdx.x;
    const int k = bid & 63;            // king; bid%8 == k%8 -> XCD pinning
    const int rest = bid >> 6;
    const int gi = rest & (MAXG - 1);  // slot group
    const int rb = rest >> 2;          // row block (0..RB-1)
    const int t = threadIdx.x, l = t & 63, g = t >> 6;
    const int p = rb * 4 + g;          // this wave's part index (0..7)
    const int r0 = rb * 320;

    const int s0 = king_start[k], s1 = king_start[k + 1];
    const int cnt = s1 - s0;
    const char* Wk = (const char*)Wv + (size_t)k * NROWS * NDIM * (RAWW ? 2 : 4);

    for (int lbase = gi * SG; lbase < cnt; lbase += MAXG * SG) {
        const int ns = min(SG, cnt - lbase);
        const unsigned emask = (ns >= 32) ? 0xFFFFu : ((1u << ns) - 1u) & 0xFFFFu;
        if (t < SG) {
            const int s = slot_list[s0 + lbase + min(t, ns - 1)];
            sh->sslot[t] = s;
            sh->ssamp[t] = s >> 1;
        }
        __syncthreads();

        // ---- stage pp bytes for SG samples, rows [r0, r0+320), coalesced ----
        for (int j = t; j < SG * 80; j += 256) {
            const int i = j / 80, c = j - i * 80;
            const int s = sh->ssamp[i];
            unsigned pk;
            if (RAWPP) {
                pk = *(const unsigned*)((const uint8_t*)ppv + (size_t)s * NFEAT + r0 + c * 4);
            } else {
                const int* q = (const int*)ppv + (size_t)s * NFEAT + r0 + c * 4;
                pk = (unsigned)(q[0] != 0) | ((unsigned)(q[1] != 0) << 8)
                   | ((unsigned)(q[2] != 0) << 16) | ((unsigned)(q[3] != 0) << 24);
            }
            sh->pps[i][c] = pk;
        }
        __syncthreads();

        // ---- build 16-bit row masks from LDS ----
        for (int r = t; r < 320; r += 256) {
            const int q = r >> 2, sh8 = (r & 3) * 8;
            unsigned mm = 0;
            #pragma unroll
            for (int i = 0; i < SG; ++i)
                mm |= (((sh->pps[i][q] >> sh8) & 0xFFu) ? 1u : 0u) << i;
            sh->mask[r] = mm & emask;
        }
        __syncthreads();

        // ---- row loop: wave g owns rows [r0+g*80, +80); one load serves 16 slots ----
        ushort4v acc[SG];
        #pragma unroll
        for (int i = 0; i < SG; ++i) acc[i] = (ushort4v)0;

        #pragma unroll 2
        for (int rr = 0; rr < 80; ++rr) {
            const int lr = g * 80 + rr;
            unsigned mm = sh->mask[lr];
            mm = __builtin_amdgcn_readfirstlane(mm);   // wave-uniform -> scalar branches
            ushort4v w;
            if (RAWW) {
                w = *(const ushort4v*)(Wk + (size_t)(r0 + lr) * 512 + (size_t)l * 8);
            } else {
                const int4 u = *(const int4*)(Wk + (size_t)(r0 + lr) * 1024 + (size_t)l * 16);
                w.x = (unsigned short)u.x; w.y = (unsigned short)u.y;
                w.z = (unsigned short)u.z; w.w = (unsigned short)u.w;
            }
            #pragma unroll
            for (int i = 0; i < SG; ++i)
                if (mm & (1u << i)) acc[i] += w;       // 2x v_pk_add_u16, mod 2^16 exact
        }

        // ---- write this wave's u16 partial slice (no cross-wave reduce) ----
        #pragma unroll
        for (int i = 0; i < SG; ++i) {
            if (i < ns) {
                const int slot = sh->sslot[i];
                *(ushort4v*)&partial[((size_t)p * nslots + slot) * NDIM + 4 * l] = acc[i];
            }
        }
        __syncthreads();   // protect LDS before next pass
    }
}

__global__ __launch_bounds__(256) void nnue_gather(
    const void* __restrict__ pp, const void* __restrict__ W,
    const int* __restrict__ ws, const int* __restrict__ king_start,
    const int* __restrict__ slot_list, unsigned short* __restrict__ partial,
    int nslots)
{
    __shared__ GaLds sh;
    const int raww = ws[1], rawpp = ws[2];
    if (raww) {
        if (rawpp) gather_body<true,  true >(pp, W, king_start, slot_list, partial, nslots, &sh);
        else       gather_body<true,  false>(pp, W, king_start, slot_list, partial, nslots, &sh);
    } else {
        if (rawpp) gather_body<false, true >(pp, W, king_start, slot_list, partial, nslots, &sh);
        else       gather_body<false, false>(pp, W, king_start, slot_list, partial, nslots, &sh);
    }
}

// ============================ combine + FC + finalize ============================
struct CbLds {
    alignas(16) int8_t x[NDIM];
    int fc[256];
    alignas(4) int8_t x2[32];
};

template<bool RAWW>
__device__ __forceinline__ void combine_body(
    const unsigned short* __restrict__ partial, const int* __restrict__ kp,
    const void* __restrict__ Wv, const void* __restrict__ ibv,
    const void* __restrict__ w1v, const int* __restrict__ b1,
    const void* __restrict__ w2v, const int* __restrict__ b2,
    const void* __restrict__ owv, const int* __restrict__ ob,
    int* __restrict__ ws, int* __restrict__ out, int nslots, CbLds* sh)
{
    const int b = blockIdx.x;
    const int t = threadIdx.x;
    const int k0 = kp[2 * b + 0];
    const int k1 = kp[2 * b + 1];
    {
        unsigned tot = 0;  // u16 sums carried in u32; truncate at end (mod 2^16 exact)
        #pragma unroll
        for (int pi = 0; pi < PARTS; ++pi) {
            tot += partial[((size_t)pi * nslots + 2 * b + 0) * NDIM + t];
            tot += partial[((size_t)pi * nslots + 2 * b + 1) * NDIM + t];
        }
        if (RAWW) {
            const uint16_t* Wq = (const uint16_t*)Wv;
            tot += Wq[((size_t)k0 * NROWS + NFEAT) * NDIM + t];
            tot += Wq[((size_t)k1 * NROWS + NFEAT) * NDIM + t];
            tot += ((const uint16_t*)ibv)[t];
        } else {
            const int* Wq = (const int*)Wv;
            tot += (unsigned)Wq[((size_t)k0 * NROWS + NFEAT) * NDIM + t];
            tot += (unsigned)Wq[((size_t)k1 * NROWS + NFEAT) * NDIM + t];
            tot += (unsigned)((const int*)ibv)[t];
        }
        int v = (int)(int16_t)(uint16_t)tot;   // int16 wraparound semantics
        v = v < 0 ? 0 : (v > 127 ? 127 : v);
        sh->x[t] = (int8_t)v;
    }
    __syncthreads();

    // ---- FC1: 32 outputs over concat([x,x]) = fold the two 256-halves of w1 ----
    {
        const int o = t >> 3, part = t & 7;
        int y = 0;
        const uint32_t* xw = (const uint32_t*)sh->x;
        if (RAWW) {
            const uint32_t* w1r = (const uint32_t*)((const char*)w1v + o * 512);
            #pragma unroll
            for (int i = 0; i < 8; ++i) {
                const int wi = part * 8 + i;
                const uint32_t xv = xw[wi];
                const uint32_t wa = w1r[wi];
                const uint32_t wb = w1r[64 + wi];
                #pragma unroll
                for (int jj = 0; jj < 4; ++jj) {
                    const int xj  = (int)((xv >> (8 * jj)) & 0xFFu);
                    const int waj = (int)(int8_t)(uint8_t)(wa >> (8 * jj));
                    const int wbj = (int)(int8_t)(uint8_t)(wb >> (8 * jj));
                    y += xj * (waj + wbj);
                }
            }
        } else {
            const int* w1r = (const int*)w1v + o * 512;
            #pragma unroll
            for (int i = 0; i < 8; ++i) {
                const int wi = part * 8 + i;
                const uint32_t xv = xw[wi];
                #pragma unroll
                for (int jj = 0; jj < 4; ++jj) {
                    const int xj = (int)((xv >> (8 * jj)) & 0xFFu);
                    y += xj * (w1r[wi * 4 + jj] + w1r[256 + wi * 4 + jj]);
                }
            }
        }
        sh->fc[t] = y;
    }
    __syncthreads();

    if (t < 32) {
        int y = b1[t];
        #pragma unroll
        for (int pq = 0; pq < 8; ++pq) y += sh->fc[t * 8 + pq];
        y >>= 6;                                  // floor_divide(y, 64)
        y = y < 0 ? 0 : (y > 127 ? 127 : y);
        sh->x2[t] = (int8_t)y;
    }
    __syncthreads();

    if (t < 32) {
        int y = b2[t];
        const uint32_t* x2w = (const uint32_t*)sh->x2;
        if (RAWW) {
            const uint32_t* w2r = (const uint32_t*)((const char*)w2v + t * 32);
            #pragma unroll
            for (int i = 0; i < 8; ++i) {
                const uint32_t xv = x2w[i];
                const uint32_t wv = w2r[i];
                #pragma unroll
                for (int jj = 0; jj < 4; ++jj)
                    y += (int)((xv >> (8 * jj)) & 0xFFu) * (int)(int8_t)(uint8_t)(wv >> (8 * jj));
            }
        } else {
            const int* w2r = (const int*)w2v + t * 32;
            #pragma unroll
            for (int i = 0; i < 8; ++i) {
                const uint32_t xv = x2w[i];
                #pragma unroll
                for (int jj = 0; jj < 4; ++jj)
                    y += (int)((xv >> (8 * jj)) & 0xFFu) * w2r[i * 4 + jj];
            }
        }
        y >>= 6;
        y = y < 0 ? 0 : (y > 127 ? 127 : y);
        const int owx = RAWW ? (int)((const int8_t*)owv)[t] : ((const int*)owv)[t];
        int pr = y * owx;
        #pragma unroll
        for (int off = 16; off > 0; off >>= 1) pr += __shfl_down(pr, off, 32);
        if (t == 0) {
            atomicAdd(ws, pr);
            __threadfence();                       // make my add visible before signaling done
            const int prev = atomicAdd(ws + 3, 1);
            if (prev == (int)gridDim.x - 1) {      // last block finalizes
                __threadfence();
                const int s = atomicAdd(ws, 0);    // atomic read of the total
                out[0] = (s + ob[0]) >> 4;         // floor_divide(s, 16)
            }
        }
    }
}

__global__ __launch_bounds__(256) void nnue_combine(
    const unsigned short* __restrict__ partial, const int* __restrict__ kp,
    const void* __restrict__ W, const void* __restrict__ ib,
    const void* __restrict__ w1, const int* __restrict__ b1,
    const void* __restrict__ w2, const int* __restrict__ b2,
    const void* __restrict__ ow, const int* __restrict__ ob,
    int* __restrict__ ws, int* __restrict__ out, int nslots)
{
    __shared__ CbLds sh;
    if (ws[1]) combine_body<true >(partial, kp, W, ib, w1, b1, w2, b2, ow, ob, ws, out, nslots, &sh);
    else       combine_body<false>(partial, kp, W, ib, w1, b1, w2, b2, ow, ob, ws, out, nslots, &sh);
}

// ============================ fallback (round-1 monolithic, proven) ============================
struct SharedBuf {
    uint8_t pp[NFEAT];
    int     acc[4][NDIM];
    alignas(16) int8_t x[NDIM];
    int     fc[256];
    alignas(4) int8_t x2[32];
    int     list[4][160];
};

__global__ void detect_layout(const int* __restrict__ W32, const int* __restrict__ pp32,
                              int* __restrict__ ws) {
    int raww = 0, rawpp = 0;
    for (int i = 0; i < 16; ++i) {
        const int v = W32[i];
        if (v > 32767 || v < -32768) raww = 1;
        const int u = pp32[i];
        if (u != 0 && u != 1) rawpp = 1;
    }
    ws[0] = 0; ws[1] = raww; ws[2] = rawpp;
}

template<bool RAWW, bool RAWPP>
__device__ __forceinline__ void mono_body(
    const void* __restrict__ ppv, const int* __restrict__ kp,
    const void* __restrict__ Wv,  const void* __restrict__ ibv,
    const void* __restrict__ w1v, const int* __restrict__ b1,
    const void* __restrict__ w2v, const int* __restrict__ b2,
    const void* __restrict__ owv, int* __restrict__ ws, SharedBuf& sh)
{
    const int b = blockIdx.x;
    const int t = threadIdx.x;
    const int l = t & 63;
    const int g = t >> 6;

    if (RAWPP) {
        const uint32_t* src = (const uint32_t*)((const uint8_t*)ppv + (size_t)b * NFEAT);
        if (t < NFEAT / 4) ((uint32_t*)sh.pp)[t] = src[t];
    } else {
        const int* src = (const int*)ppv + (size_t)b * NFEAT;
        for (int i = t; i < NFEAT; i += 256) sh.pp[i] = (uint8_t)(src[i] != 0);
    }
    __syncthreads();

    const int base = g * 160;
    int cnt = 0;
    for (int c = 0; c < 160; c += 64) {
        const int idx = c + l;
        const bool flag = (idx < 160) && (sh.pp[base + idx] != 0);
        const unsigned long long mmask = __ballot(flag);
        const int pos = cnt + (int)__popcll(mmask & ((1ull << l) - 1ull));
        if (flag) sh.list[g][pos] = base + idx;
        cnt += (int)__popcll(mmask);
    }

    const int k0 = kp[b * 2 + 0];
    const int k1 = kp[b * 2 + 1];
    int a0 = 0, a1 = 0, a2 = 0, a3 = 0, a4 = 0, a5 = 0, a6 = 0, a7 = 0;

    if (RAWW) {
        const char* W0 = (const char*)Wv + (size_t)k0 * (NROWS * NDIM * 2);
        const char* W1 = (const char*)Wv + (size_t)k1 * (NROWS * NDIM * 2);
        const int lo = l * 8;
        auto step = [&](int f) {
            const uint2 u0 = *(const uint2*)(W0 + f * 512 + lo);
            const uint2 u1 = *(const uint2*)(W1 + f * 512 + lo);
            a0 += (int)(u0.x & 0xFFFFu); a1 += (int)(u0.x >> 16);
            a2 += (int)(u0.y & 0xFFFFu); a3 += (int)(u0.y >> 16);
            a4 += (int)(u1.x & 0xFFFFu); a5 += (int)(u1.x >> 16);
            a6 += (int)(u1.y & 0xFFFFu); a7 += (int)(u1.y >> 16);
        };
        int j = 0;
        for (; j + 4 <= cnt; j += 4) {
            const int f0 = sh.list[g][j], f1 = sh.list[g][j + 1];
            const int f2 = sh.list[g][j + 2], f3 = sh.list[g][j + 3];
            step(f0); step(f1); step(f2); step(f3);
        }
        for (; j < cnt; ++j) step(sh.list[g][j]);
    } else {
        const char* W0 = (const char*)Wv + (size_t)k0 * (NROWS * NDIM * 4);
        const char* W1 = (const char*)Wv + (size_t)k1 * (NROWS * NDIM * 4);
        const int lo = l * 16;
        auto step = [&](int f) {
            const int4 u0 = *(const int4*)(W0 + f * 1024 + lo);
            const int4 u1 = *(const int4*)(W1 + f * 1024 + lo);
            a0 += u0.x; a1 += u0.y; a2 += u0.z; a3 += u0.w;
            a4 += u1.x; a5 += u1.y; a6 += u1.z; a7 += u1.w;
        };
        int j = 0;
        for (; j + 4 <= cnt; j += 4) {
            const int f0 = sh.list[g][j], f1 = sh.list[g][j + 1];
            const int f2 = sh.list[g][j + 2], f3 = sh.list[g][j + 3];
            step(f0); step(f1); step(f2); step(f3);
        }
        for (; j < cnt; ++j) step(sh.list[g][j]);
    }

    sh.acc[g][4 * l + 0] = a0 + a4;
    sh.acc[g][4 * l + 1] = a1 + a5;
    sh.acc[g][4 * l + 2] = a2 + a6;
    sh.acc[g][4 * l + 3] = a3 + a7;
    __syncthreads();

    {
        const int d = t;
        int tot = sh.acc[0][d] + sh.acc[1][d] + sh.acc[2][d] + sh.acc[3][d];
        int kb0, kb1, ibx;
        if (RAWW) {
            const int16_t* Wq = (const int16_t*)Wv;
            kb0 = Wq[((size_t)k0 * NROWS + NFEAT) * NDIM + d];
            kb1 = Wq[((size_t)k1 * NROWS + NFEAT) * NDIM + d];
            ibx = ((const int16_t*)ibv)[d];
        } else {
            const int* Wq = (const int*)Wv;
            kb0 = Wq[((size_t)k0 * NROWS + NFEAT) * NDIM + d];
            kb1 = Wq[((size_t)k1 * NROWS + NFEAT) * NDIM + d];
            ibx = ((const int*)ibv)[d];
        }
        tot += kb0 + kb1 + ibx;
        int v = (int)(int16_t)(uint16_t)(uint32_t)tot;
        v = v < 0 ? 0 : (v > 127 ? 127 : v);
        sh.x[d] = (int8_t)v;
    }
    __syncthreads();

    {
        const int o = t >> 3, part = t & 7;
        int y = 0;
        const uint32_t* xw = (const uint32_t*)sh.x;
        if (RAWW) {
            const uint32_t* w1r = (const uint32_t*)((const char*)w1v + o * 512);
            #pragma unroll
            for (int i = 0; i < 8; ++i) {
                const int wi = part * 8 + i;
                const uint32_t xv = xw[wi];
                const uint32_t wa = w1r[wi];
                const uint32_t wb = w1r[64 + wi];
                #pragma unroll
                for (int jj = 0; jj < 4; ++jj) {
                    const int xj  = (int)((xv >> (8 * jj)) & 0xFFu);
                    const int waj = (int)(int8_t)(uint8_t)(wa >> (8 * jj));
                    const int wbj = (int)(int8_t)(uint8_t)(wb >> (8 * jj));
                    y += xj * (waj + wbj);
                }
            }
        } else {
            const int* w1r = (const int*)w1v + o * 512;
            #pragma unroll
            for (int i = 0; i < 8; ++i) {
                const int wi = part * 8 + i;
                const uint32_t xv = xw[wi];
                #pragma unroll
                for (int jj = 0; jj < 4; ++jj) {
                    const int xj = (int)((xv >> (8 * jj)) & 0xFFu);
                    y += xj * (w1r[wi * 4 + jj] + w1r[256 + wi * 4 + jj]);
                }
            }
        }
        sh.fc[t] = y;
    }
    __syncthreads();

    if (t < 32) {
        int y = b1[t];
        #pragma unroll
        for (int pq = 0; pq < 8; ++pq) y += sh.fc[t * 8 + pq];
        y >>= 6;
        y = y < 0 ? 0 : (y > 127 ? 127 : y);
        sh.x2[t] = (int8_t)y;
    }
    __syncthreads();

    if (t < 32) {
        int y = b2[t];
        const uint32_t* x2w = (const uint32_t*)sh.x2;
        if (RAWW) {
            const uint32_t* w2r = (const uint32_t*)((const char*)w2v + t * 32);
            #pragma unroll
            for (int i = 0; i < 8; ++i) {
                const uint32_t xv = x2w[i];
                const uint32_t wv = w2r[i];
                #pragma unroll
                for (int jj = 0; jj < 4; ++jj)
                    y += (int)((xv >> (8 * jj)) & 0xFFu) * (int)(int8_t)(uint8_t)(wv >> (8 * jj));
            }
        } else {
            const int* w2r = (const int*)w2v + t * 32;
            #pragma unroll
            for (int i = 0; i < 8; ++i) {
                const uint32_t xv = x2w[i];
                #pragma unroll
                for (int jj = 0; jj < 4; ++jj)
                    y += (int)((xv >> (8 * jj)) & 0xFFu) * w2r[i * 4 + jj];
            }
        }
        y >>= 6;
        y = y < 0 ? 0 : (y > 127 ? 127 : y);
        const int owx = RAWW ? (int)((const int8_t*)owv)[t] : ((const int*)owv)[t];
        int pr = y * owx;
        #pragma unroll
        for (int off = 16; off > 0; off >>= 1) pr += __shfl_down(pr, off, 32);
        if (t == 0) atomicAdd(ws, pr);
    }
}

__global__ __launch_bounds__(256, 4) void nnue_mono(
    const void* __restrict__ pp, const int* __restrict__ kp,
    const void* __restrict__ W,  const void* __restrict__ ib,
    const void* __restrict__ w1, const int* __restrict__ b1,
    const void* __restrict__ w2, const int* __restrict__ b2,
    const void* __restrict__ ow, int* __restrict__ ws)
{
    __shared__ SharedBuf sh;
    const int raww = ws[1], rawpp = ws[2];
    if (raww) {
        if (rawpp) mono_body<true,  true >(pp, kp, W, ib, w1, b1, w2, b2, ow, ws, sh);
        else       mono_body<true,  false>(pp, kp, W, ib, w1, b1, w2, b2, ow, ws, sh);
    } else {
        if (rawpp) mono_body<false, true >(pp, kp, W, ib, w1, b1, w2, b2, ow, ws, sh);
        else       mono_body<false, false>(pp, kp, W, ib, w1, b1, w2, b2, ow, ws, sh);
    }
}

__global__ void nnue_finalize(const int* __restrict__ ws, const int* __restrict__ ob,
                              int* __restrict__ out) {
    out[0] = (ws[0] + ob[0]) >> 4;
}

// ============================ host launch ============================
extern "C" void kernel_launch(void* const* d_in, const int* in_sizes, int n_in,
                              void* d_out, int out_size, void* d_ws, size_t ws_size,
                              hipStream_t stream)
{
    const void* pp = d_in[0];
    const int*  kp = (const int*)d_in[1];
    const void* W  = d_in[2];
    const void* ib = d_in[3];
    const void* w1 = d_in[4];
    const int*  b1 = (const int*)d_in[5];
    const void* w2 = d_in[6];
    const int*  b2 = (const int*)d_in[7];
    const void* ow = d_in[8];
    const int*  ob = (const int*)d_in[9];
    int* ws  = (int*)d_ws;
    int* out = (int*)d_out;

    const int B = in_sizes[1] / 2;   // king_positions is (B, 2)
    const int nslots = 2 * B;

    // ws layout (int offsets): [0..3] flags/sum/done, [16..80] king_start,
    // [96..96+nslots) slot_list, u16 partial after 256-int alignment
    const size_t off_ks = 16;
    const size_t off_sl = 96;
    const size_t off_pb = ((off_sl + (size_t)nslots + 255) / 256) * 256;
    const size_t need   = (off_pb + (size_t)PARTS * nslots * (NDIM / 2)) * 4;

    if (ws_size >= need) {
        int* king_start = ws + off_ks;
        int* slot_list  = ws + off_sl;
        unsigned short* partial = (unsigned short*)(ws + off_pb);

        hipLaunchKernelGGL(nnue_bucket, dim3(1), dim3(256), 0, stream,
                           kp, (const int*)W, (const int*)pp, nslots,
                           ws, king_start, slot_list);
        hipLaunchKernelGGL(nnue_gather, dim3(64 * MAXG * RB), dim3(256), 0, stream,
                           pp, W, ws, king_start, slot_list, partial, nslots);
        hipLaunchKernelGGL(nnue_combine, dim3(B), dim3(256), 0, stream,
                           partial, kp, W, ib, w1, b1, w2, b2, ow, ob, ws, out, nslots);
    } else {
        // fallback: round-1 monolithic path (proven)
        hipLaunchKernelGGL(detect_layout, dim3(1), dim3(1), 0, stream,
                           (const int*)W, (const int*)pp, ws);
        hipLaunchKernelGGL(nnue_mono, dim3(B), dim3(256), 0, stream,
                           pp, kp, W, ib, w1, b1, w2, b2, ow, ws);
        hipLaunchKernelGGL(nnue_finalize, dim3(1), dim3(1), 0, stream, ws, ob, out);
    }
}

// Round 6
// 166.101 us; speedup vs baseline: 3.3878x; 1.0042x over previous
//
#include <hip/hip_runtime.h>
#include <stdint.h>

#define NDIM  256   // accumulator width
#define NFEAT 640   // piece features per sample
#define NROWS 641   // 640 features + 1 king bias row
#define SG    8     // slots per group
#define MAXG  4     // slot-group blocks per (king,row-block); stride loop covers overflow
#define RB    4     // row-blocks (160 rows each); PARTS = RB*4 waves
#define PARTS 16

typedef unsigned short ushort4v __attribute__((ext_vector_type(4)));

// ============================ bucket + detect ============================
// ws[0]=scalar sum, ws[1]=raw-int16 weights, ws[2]=raw-bool pp, ws[3]=done counter
__global__ void nnue_bucket(const int* __restrict__ kp, const int* __restrict__ W32,
                            const int* __restrict__ pp32, int nslots,
                            int* __restrict__ ws,
                            int* __restrict__ king_start, int* __restrict__ slot_list)
{
    __shared__ int cnt[64];
    __shared__ int off[64];
    const int t = threadIdx.x;
    if (t < 64) cnt[t] = 0;
    if (t == 0) {
        int raww = 0, rawpp = 0;
        for (int i = 0; i < 16; ++i) {
            const int v = W32[i];                     // int32 layout => |v| <= 32767
            if (v > 32767 || v < -32768) raww = 1;    // packed int16 pairs look huge
            const int u = pp32[i];                    // int32 layout => {0,1}
            if (u != 0 && u != 1) rawpp = 1;          // packed bool bytes exceed 1
        }
        ws[0] = 0; ws[1] = raww; ws[2] = rawpp; ws[3] = 0;
    }
    __syncthreads();
    for (int s = t; s < nslots; s += 256) atomicAdd(&cnt[kp[s]], 1);
    __syncthreads();
    if (t == 0) {
        int run = 0;
        for (int k = 0; k < 64; ++k) { off[k] = run; king_start[k] = run; run += cnt[k]; }
        king_start[64] = run;
    }
    __syncthreads();
    for (int s = t; s < nslots; s += 256) {
        const int k = kp[s];
        const int pos = atomicAdd(&off[k], 1);
        slot_list[pos] = s;        // s = 2*sample + side; partial indexed by slot id directly
    }
}

// ============================ king-major gather ============================
struct GaLds {
    unsigned pps[SG][40];   // staged pp bytes: sample i, 160 rows (byte per row)
    unsigned mask[160];     // 8-bit activity mask per row
    int sslot[SG];          // slot ids
    int ssamp[SG];          // sample ids
};

template<bool RAWW, bool RAWPP>
__device__ __forceinline__ void gather_body(
    const void* __restrict__ ppv, const void* __restrict__ Wv,
    const int* __restrict__ king_start, const int* __restrict__ slot_list,
    unsigned short* __restrict__ partial, int nslots, GaLds* sh)
{
    const int bid = blockIdx.x;
    const int k = bid & 63;            // king; bid%8 == k%8 -> XCD pinning (L2 locality)
    const int rest = bid >> 6;
    const int gi = rest & (MAXG - 1);  // slot group
    const int rb = rest >> 2;          // row block (0..RB-1)
    const int t = threadIdx.x, l = t & 63, g = t >> 6;
    const int p = rb * 4 + g;          // this wave's part index (0..PARTS-1)
    const int r0 = rb * 160;

    const int s0 = king_start[k], s1 = king_start[k + 1];
    const int cnt = s1 - s0;
    const char* Wk = (const char*)Wv + (size_t)k * NROWS * NDIM * (RAWW ? 2 : 4);

    for (int lbase = gi * SG; lbase < cnt; lbase += MAXG * SG) {
        const int ns = min(SG, cnt - lbase);
        const unsigned emask = (1u << ns) - 1u;
        if (t < SG) {
            const int s = slot_list[s0 + lbase + min(t, ns - 1)];
            sh->sslot[t] = s;
            sh->ssamp[t] = s >> 1;
        }
        __syncthreads();

        // ---- stage pp bytes for SG samples, rows [r0, r0+160), coalesced ----
        for (int j = t; j < SG * 40; j += 256) {
            const int i = j / 40, c = j - i * 40;
            const int s = sh->ssamp[i];
            unsigned pk;
            if (RAWPP) {
                pk = *(const unsigned*)((const uint8_t*)ppv + (size_t)s * NFEAT + r0 + c * 4);
            } else {
                const int* q = (const int*)ppv + (size_t)s * NFEAT + r0 + c * 4;
                pk = (unsigned)(q[0] != 0) | ((unsigned)(q[1] != 0) << 8)
                   | ((unsigned)(q[2] != 0) << 16) | ((unsigned)(q[3] != 0) << 24);
            }
            sh->pps[i][c] = pk;
        }
        __syncthreads();

        // ---- build 8-bit row masks from LDS ----
        if (t < 160) {
            const int q = t >> 2, sh8 = (t & 3) * 8;
            unsigned mm = 0;
            #pragma unroll
            for (int i = 0; i < SG; ++i)
                mm |= (((sh->pps[i][q] >> sh8) & 0xFFu) ? 1u : 0u) << i;
            sh->mask[t] = mm & emask;
        }
        __syncthreads();

        // ---- row loop: wave g owns rows [r0+g*40, +40); branchless masked adds ----
        ushort4v acc[SG];
        #pragma unroll
        for (int i = 0; i < SG; ++i) acc[i] = (ushort4v)0;

        #pragma unroll 4
        for (int rr = 0; rr < 40; ++rr) {
            const int lr = g * 40 + rr;
            const unsigned mm = (unsigned)__builtin_amdgcn_readfirstlane((int)sh->mask[lr]);
            uint2 wu;
            if (RAWW) {
                wu = *(const uint2*)(Wk + (size_t)(r0 + lr) * 512 + (size_t)l * 8);
            } else {
                const int4 u = *(const int4*)(Wk + (size_t)(r0 + lr) * 1024 + (size_t)l * 16);
                wu.x = ((unsigned)u.x & 0xFFFFu) | ((unsigned)u.y << 16);
                wu.y = ((unsigned)u.z & 0xFFFFu) | ((unsigned)u.w << 16);
            }
            #pragma unroll
            for (int i = 0; i < SG; ++i) {
                const unsigned sel = 0u - ((mm >> i) & 1u);   // scalar 0 or ~0
                uint2 m; m.x = wu.x & sel; m.y = wu.y & sel;  // 2x v_and (sgpr operand)
                ushort4v mv;
                __builtin_memcpy(&mv, &m, 8);
                acc[i] += mv;                                 // 2x v_pk_add_u16, mod 2^16 exact
            }
        }

        // ---- write this wave's u16 partial slice (no cross-wave reduce) ----
        #pragma unroll
        for (int i = 0; i < SG; ++i) {
            if (i < ns) {
                const int slot = sh->sslot[i];
                *(ushort4v*)&partial[((size_t)p * nslots + slot) * NDIM + 4 * l] = acc[i];
            }
        }
        __syncthreads();   // protect LDS before next pass
    }
}

__global__ __launch_bounds__(256) void nnue_gather(
    const void* __restrict__ pp, const void* __restrict__ W,
    const int* __restrict__ ws, const int* __restrict__ king_start,
    const int* __restrict__ slot_list, unsigned short* __restrict__ partial,
    int nslots)
{
    __shared__ GaLds sh;
    const int raww = ws[1], rawpp = ws[2];
    if (raww) {
        if (rawpp) gather_body<true,  true >(pp, W, king_start, slot_list, partial, nslots, &sh);
        else       gather_body<true,  false>(pp, W, king_start, slot_list, partial, nslots, &sh);
    } else {
        if (rawpp) gather_body<false, true >(pp, W, king_start, slot_list, partial, nslots, &sh);
        else       gather_body<false, false>(pp, W, king_start, slot_list, partial, nslots, &sh);
    }
}

// ============================ combine + FC + finalize ============================
struct CbLds {
    alignas(16) int8_t x[NDIM];
    int fc[256];
    alignas(4) int8_t x2[32];
};

template<bool RAWW>
__device__ __forceinline__ void combine_body(
    const unsigned short* __restrict__ partial, const int* __restrict__ kp,
    const void* __restrict__ Wv, const void* __restrict__ ibv,
    const void* __restrict__ w1v, const int* __restrict__ b1,
    const void* __restrict__ w2v, const int* __restrict__ b2,
    const void* __restrict__ owv, const int* __restrict__ ob,
    int* __restrict__ ws, int* __restrict__ out, int nslots, CbLds* sh)
{
    const int b = blockIdx.x;
    const int t = threadIdx.x;
    const int k0 = kp[2 * b + 0];
    const int k1 = kp[2 * b + 1];
    {
        unsigned tot = 0;  // u16 sums carried in u32; truncate at end (mod 2^16 exact)
        #pragma unroll
        for (int pi = 0; pi < PARTS; ++pi) {
            tot += partial[((size_t)pi * nslots + 2 * b + 0) * NDIM + t];
            tot += partial[((size_t)pi * nslots + 2 * b + 1) * NDIM + t];
        }
        if (RAWW) {
            const uint16_t* Wq = (const uint16_t*)Wv;
            tot += Wq[((size_t)k0 * NROWS + NFEAT) * NDIM + t];
            tot += Wq[((size_t)k1 * NROWS + NFEAT) * NDIM + t];
            tot += ((const uint16_t*)ibv)[t];
        } else {
            const int* Wq = (const int*)Wv;
            tot += (unsigned)Wq[((size_t)k0 * NROWS + NFEAT) * NDIM + t];
            tot += (unsigned)Wq[((size_t)k1 * NROWS + NFEAT) * NDIM + t];
            tot += (unsigned)((const int*)ibv)[t];
        }
        int v = (int)(int16_t)(uint16_t)tot;   // int16 wraparound semantics
        v = v < 0 ? 0 : (v > 127 ? 127 : v);
        sh->x[t] = (int8_t)v;
    }
    __syncthreads();

    // ---- FC1: 32 outputs over concat([x,x]) = fold the two 256-halves of w1 ----
    {
        const int o = t >> 3, part = t & 7;
        int y = 0;
        const uint32_t* xw = (const uint32_t*)sh->x;
        if (RAWW) {
            const uint32_t* w1r = (const uint32_t*)((const char*)w1v + o * 512);
            #pragma unroll
            for (int i = 0; i < 8; ++i) {
                const int wi = part * 8 + i;
                const uint32_t xv = xw[wi];
                const uint32_t wa = w1r[wi];
                const uint32_t wb = w1r[64 + wi];
                #pragma unroll
                for (int jj = 0; jj < 4; ++jj) {
                    const int xj  = (int)((xv >> (8 * jj)) & 0xFFu);
                    const int waj = (int)(int8_t)(uint8_t)(wa >> (8 * jj));
                    const int wbj = (int)(int8_t)(uint8_t)(wb >> (8 * jj));
                    y += xj * (waj + wbj);
                }
            }
        } else {
            const int* w1r = (const int*)w1v + o * 512;
            #pragma unroll
            for (int i = 0; i < 8; ++i) {
                const int wi = part * 8 + i;
                const uint32_t xv = xw[wi];
                #pragma unroll
                for (int jj = 0; jj < 4; ++jj) {
                    const int xj = (int)((xv >> (8 * jj)) & 0xFFu);
                    y += xj * (w1r[wi * 4 + jj] + w1r[256 + wi * 4 + jj]);
                }
            }
        }
        sh->fc[t] = y;
    }
    __syncthreads();

    if (t < 32) {
        int y = b1[t];
        #pragma unroll
        for (int pq = 0; pq < 8; ++pq) y += sh->fc[t * 8 + pq];
        y >>= 6;                                  // floor_divide(y, 64)
        y = y < 0 ? 0 : (y > 127 ? 127 : y);
        sh->x2[t] = (int8_t)y;
    }
    __syncthreads();

    if (t < 32) {
        int y = b2[t];
        const uint32_t* x2w = (const uint32_t*)sh->x2;
        if (RAWW) {
            const uint32_t* w2r = (const uint32_t*)((const char*)w2v + t * 32);
            #pragma unroll
            for (int i = 0; i < 8; ++i) {
                const uint32_t xv = x2w[i];
                const uint32_t wv = w2r[i];
                #pragma unroll
                for (int jj = 0; jj < 4; ++jj)
                    y += (int)((xv >> (8 * jj)) & 0xFFu) * (int)(int8_t)(uint8_t)(wv >> (8 * jj));
            }
        } else {
            const int* w2r = (const int*)w2v + t * 32;
            #pragma unroll
            for (int i = 0; i < 8; ++i) {
                const uint32_t xv = x2w[i];
                #pragma unroll
                for (int jj = 0; jj < 4; ++jj)
                    y += (int)((xv >> (8 * jj)) & 0xFFu) * w2r[i * 4 + jj];
            }
        }
        y >>= 6;
        y = y < 0 ? 0 : (y > 127 ? 127 : y);
        const int owx = RAWW ? (int)((const int8_t*)owv)[t] : ((const int*)owv)[t];
        int pr = y * owx;
        #pragma unroll
        for (int off = 16; off > 0; off >>= 1) pr += __shfl_down(pr, off, 32);
        if (t == 0) {
            atomicAdd(ws, pr);
            __threadfence();                       // make my add visible before signaling done
            const int prev = atomicAdd(ws + 3, 1);
            if (prev == (int)gridDim.x - 1) {      // last block finalizes
                __threadfence();
                const int s = atomicAdd(ws, 0);    // atomic read of the total
                out[0] = (s + ob[0]) >> 4;         // floor_divide(s, 16)
            }
        }
    }
}

__global__ __launch_bounds__(256) void nnue_combine(
    const unsigned short* __restrict__ partial, const int* __restrict__ kp,
    const void* __restrict__ W, const void* __restrict__ ib,
    const void* __restrict__ w1, const int* __restrict__ b1,
    const void* __restrict__ w2, const int* __restrict__ b2,
    const void* __restrict__ ow, const int* __restrict__ ob,
    int* __restrict__ ws, int* __restrict__ out, int nslots)
{
    __shared__ CbLds sh;
    if (ws[1]) combine_body<true >(partial, kp, W, ib, w1, b1, w2, b2, ow, ob, ws, out, nslots, &sh);
    else       combine_body<false>(partial, kp, W, ib, w1, b1, w2, b2, ow, ob, ws, out, nslots, &sh);
}

// ============================ fallback (round-1 monolithic, proven) ============================
struct SharedBuf {
    uint8_t pp[NFEAT];
    int     acc[4][NDIM];
    alignas(16) int8_t x[NDIM];
    int     fc[256];
    alignas(4) int8_t x2[32];
    int     list[4][160];
};

__global__ void detect_layout(const int* __restrict__ W32, const int* __restrict__ pp32,
                              int* __restrict__ ws) {
    int raww = 0, rawpp = 0;
    for (int i = 0; i < 16; ++i) {
        const int v = W32[i];
        if (v > 32767 || v < -32768) raww = 1;
        const int u = pp32[i];
        if (u != 0 && u != 1) rawpp = 1;
    }
    ws[0] = 0; ws[1] = raww; ws[2] = rawpp;
}

template<bool RAWW, bool RAWPP>
__device__ __forceinline__ void mono_body(
    const void* __restrict__ ppv, const int* __restrict__ kp,
    const void* __restrict__ Wv,  const void* __restrict__ ibv,
    const void* __restrict__ w1v, const int* __restrict__ b1,
    const void* __restrict__ w2v, const int* __restrict__ b2,
    const void* __restrict__ owv, int* __restrict__ ws, SharedBuf& sh)
{
    const int b = blockIdx.x;
    const int t = threadIdx.x;
    const int l = t & 63;
    const int g = t >> 6;

    if (RAWPP) {
        const uint32_t* src = (const uint32_t*)((const uint8_t*)ppv + (size_t)b * NFEAT);
        if (t < NFEAT / 4) ((uint32_t*)sh.pp)[t] = src[t];
    } else {
        const int* src = (const int*)ppv + (size_t)b * NFEAT;
        for (int i = t; i < NFEAT; i += 256) sh.pp[i] = (uint8_t)(src[i] != 0);
    }
    __syncthreads();

    const int base = g * 160;
    int cnt = 0;
    for (int c = 0; c < 160; c += 64) {
        const int idx = c + l;
        const bool flag = (idx < 160) && (sh.pp[base + idx] != 0);
        const unsigned long long mmask = __ballot(flag);
        const int pos = cnt + (int)__popcll(mmask & ((1ull << l) - 1ull));
        if (flag) sh.list[g][pos] = base + idx;
        cnt += (int)__popcll(mmask);
    }

    const int k0 = kp[b * 2 + 0];
    const int k1 = kp[b * 2 + 1];
    int a0 = 0, a1 = 0, a2 = 0, a3 = 0, a4 = 0, a5 = 0, a6 = 0, a7 = 0;

    if (RAWW) {
        const char* W0 = (const char*)Wv + (size_t)k0 * (NROWS * NDIM * 2);
        const char* W1 = (const char*)Wv + (size_t)k1 * (NROWS * NDIM * 2);
        const int lo = l * 8;
        auto step = [&](int f) {
            const uint2 u0 = *(const uint2*)(W0 + f * 512 + lo);
            const uint2 u1 = *(const uint2*)(W1 + f * 512 + lo);
            a0 += (int)(u0.x & 0xFFFFu); a1 += (int)(u0.x >> 16);
            a2 += (int)(u0.y & 0xFFFFu); a3 += (int)(u0.y >> 16);
            a4 += (int)(u1.x & 0xFFFFu); a5 += (int)(u1.x >> 16);
            a6 += (int)(u1.y & 0xFFFFu); a7 += (int)(u1.y >> 16);
        };
        int j = 0;
        for (; j + 4 <= cnt; j += 4) {
            const int f0 = sh.list[g][j], f1 = sh.list[g][j + 1];
            const int f2 = sh.list[g][j + 2], f3 = sh.list[g][j + 3];
            step(f0); step(f1); step(f2); step(f3);
        }
        for (; j < cnt; ++j) step(sh.list[g][j]);
    } else {
        const char* W0 = (const char*)Wv + (size_t)k0 * (NROWS * NDIM * 4);
        const char* W1 = (const char*)Wv + (size_t)k1 * (NROWS * NDIM * 4);
        const int lo = l * 16;
        auto step = [&](int f) {
            const int4 u0 = *(const int4*)(W0 + f * 1024 + lo);
            const int4 u1 = *(const int4*)(W1 + f * 1024 + lo);
            a0 += u0.x; a1 += u0.y; a2 += u0.z; a3 += u0.w;
            a4 += u1.x; a5 += u1.y; a6 += u1.z; a7 += u1.w;
        };
        int j = 0;
        for (; j + 4 <= cnt; j += 4) {
            const int f0 = sh.list[g][j], f1 = sh.list[g][j + 1];
            const int f2 = sh.list[g][j + 2], f3 = sh.list[g][j + 3];
            step(f0); step(f1); step(f2); step(f3);
        }
        for (; j < cnt; ++j) step(sh.list[g][j]);
    }

    sh.acc[g][4 * l + 0] = a0 + a4;
    sh.acc[g][4 * l + 1] = a1 + a5;
    sh.acc[g][4 * l + 2] = a2 + a6;
    sh.acc[g][4 * l + 3] = a3 + a7;
    __syncthreads();

    {
        const int d = t;
        int tot = sh.acc[0][d] + sh.acc[1][d] + sh.acc[2][d] + sh.acc[3][d];
        int kb0, kb1, ibx;
        if (RAWW) {
            const int16_t* Wq = (const int16_t*)Wv;
            kb0 = Wq[((size_t)k0 * NROWS + NFEAT) * NDIM + d];
            kb1 = Wq[((size_t)k1 * NROWS + NFEAT) * NDIM + d];
            ibx = ((const int16_t*)ibv)[d];
        } else {
            const int* Wq = (const int*)Wv;
            kb0 = Wq[((size_t)k0 * NROWS + NFEAT) * NDIM + d];
            kb1 = Wq[((size_t)k1 * NROWS + NFEAT) * NDIM + d];
            ibx = ((const int*)ibv)[d];
        }
        tot += kb0 + kb1 + ibx;
        int v = (int)(int16_t)(uint16_t)(uint32_t)tot;
        v = v < 0 ? 0 : (v > 127 ? 127 : v);
        sh.x[d] = (int8_t)v;
    }
    __syncthreads();

    {
        const int o = t >> 3, part = t & 7;
        int y = 0;
        const uint32_t* xw = (const uint32_t*)sh.x;
        if (RAWW) {
            const uint32_t* w1r = (const uint32_t*)((const char*)w1v + o * 512);
            #pragma unroll
            for (int i = 0; i < 8; ++i) {
                const int wi = part * 8 + i;
                const uint32_t xv = xw[wi];
                const uint32_t wa = w1r[wi];
                const uint32_t wb = w1r[64 + wi];
                #pragma unroll
                for (int jj = 0; jj < 4; ++jj) {
                    const int xj  = (int)((xv >> (8 * jj)) & 0xFFu);
                    const int waj = (int)(int8_t)(uint8_t)(wa >> (8 * jj));
                    const int wbj = (int)(int8_t)(uint8_t)(wb >> (8 * jj));
                    y += xj * (waj + wbj);
                }
            }
        } else {
            const int* w1r = (const int*)w1v + o * 512;
            #pragma unroll
            for (int i = 0; i < 8; ++i) {
                const int wi = part * 8 + i;
                const uint32_t xv = xw[wi];
                #pragma unroll
                for (int jj = 0; jj < 4; ++jj) {
                    const int xj = (int)((xv >> (8 * jj)) & 0xFFu);
                    y += xj * (w1r[wi * 4 + jj] + w1r[256 + wi * 4 + jj]);
                }
            }
        }
        sh.fc[t] = y;
    }
    __syncthreads();

    if (t < 32) {
        int y = b1[t];
        #pragma unroll
        for (int pq = 0; pq < 8; ++pq) y += sh.fc[t * 8 + pq];
        y >>= 6;
        y = y < 0 ? 0 : (y > 127 ? 127 : y);
        sh.x2[t] = (int8_t)y;
    }
    __syncthreads();

    if (t < 32) {
        int y = b2[t];
        const uint32_t* x2w = (const uint32_t*)sh.x2;
        if (RAWW) {
            const uint32_t* w2r = (const uint32_t*)((const char*)w2v + t * 32);
            #pragma unroll
            for (int i = 0; i < 8; ++i) {
                const uint32_t xv = x2w[i];
                const uint32_t wv = w2r[i];
                #pragma unroll
                for (int jj = 0; jj < 4; ++jj)
                    y += (int)((xv >> (8 * jj)) & 0xFFu) * (int)(int8_t)(uint8_t)(wv >> (8 * jj));
            }
        } else {
            const int* w2r = (const int*)w2v + t * 32;
            #pragma unroll
            for (int i = 0; i < 8; ++i) {
                const uint32_t xv = x2w[i];
                #pragma unroll
                for (int jj = 0; jj < 4; ++jj)
                    y += (int)((xv >> (8 * jj)) & 0xFFu) * w2r[i * 4 + jj];
            }
        }
        y >>= 6;
        y = y < 0 ? 0 : (y > 127 ? 127 : y);
        const int owx = RAWW ? (int)((const int8_t*)owv)[t] : ((const int*)owv)[t];
        int pr = y * owx;
        #pragma unroll
        for (int off = 16; off > 0; off >>= 1) pr += __shfl_down(pr, off, 32);
        if (t == 0) atomicAdd(ws, pr);
    }
}

__global__ __launch_bounds__(256, 4) void nnue_mono(
    const void* __restrict__ pp, const int* __restrict__ kp,
    const void* __restrict__ W,  const void* __restrict__ ib,
    const void* __restrict__ w1, const int* __restrict__ b1,
    const void* __restrict__ w2, const int* __restrict__ b2,
    const void* __restrict__ ow, int* __restrict__ ws)
{
    __shared__ SharedBuf sh;
    const int raww = ws[1], rawpp = ws[2];
    if (raww) {
        if (rawpp) mono_body<true,  true >(pp, kp, W, ib, w1, b1, w2, b2, ow, ws, sh);
        else       mono_body<true,  false>(pp, kp, W, ib, w1, b1, w2, b2, ow, ws, sh);
    } else {
        if (rawpp) mono_body<false, true >(pp, kp, W, ib, w1, b1, w2, b2, ow, ws, sh);
        else       mono_body<false, false>(pp, kp, W, ib, w1, b1, w2, b2, ow, ws, sh);
    }
}

__global__ void nnue_finalize(const int* __restrict__ ws, const int* __restrict__ ob,
                              int* __restrict__ out) {
    out[0] = (ws[0] + ob[0]) >> 4;
}

// ============================ host launch ============================
extern "C" void kernel_launch(void* const* d_in, const int* in_sizes, int n_in,
                              void* d_out, int out_size, void* d_ws, size_t ws_size,
                              hipStream_t stream)
{
    const void* pp = d_in[0];
    const int*  kp = (const int*)d_in[1];
    const void* W  = d_in[2];
    const void* ib = d_in[3];
    const void* w1 = d_in[4];
    const int*  b1 = (const int*)d_in[5];
    const void* w2 = d_in[6];
    const int*  b2 = (const int*)d_in[7];
    const void* ow = d_in[8];
    const int*  ob = (const int*)d_in[9];
    int* ws  = (int*)d_ws;
    int* out = (int*)d_out;

    const int B = in_sizes[1] / 2;   // king_positions is (B, 2)
    const int nslots = 2 * B;

    // ws layout (int offsets): [0..3] flags/sum/done, [16..80] king_start,
    // [96..96+nslots) slot_list, u16 partial after 256-int alignment
    const size_t off_ks = 16;
    const size_t off_sl = 96;
    const size_t off_pb = ((off_sl + (size_t)nslots + 255) / 256) * 256;
    const size_t need   = (off_pb + (size_t)PARTS * nslots * (NDIM / 2)) * 4;

    if (ws_size >= need) {
        int* king_start = ws + off_ks;
        int* slot_list  = ws + off_sl;
        unsigned short* partial = (unsigned short*)(ws + off_pb);

        hipLaunchKernelGGL(nnue_bucket, dim3(1), dim3(256), 0, stream,
                           kp, (const int*)W, (const int*)pp, nslots,
                           ws, king_start, slot_list);
        hipLaunchKernelGGL(nnue_gather, dim3(64 * MAXG * RB), dim3(256), 0, stream,
                           pp, W, ws, king_start, slot_list, partial, nslots);
        hipLaunchKernelGGL(nnue_combine, dim3(B), dim3(256), 0, stream,
                           partial, kp, W, ib, w1, b1, w2, b2, ow, ob, ws, out, nslots);
    } else {
        // fallback: round-1 monolithic path (proven)
        hipLaunchKernelGGL(detect_layout, dim3(1), dim3(1), 0, stream,
                           (const int*)W, (const int*)pp, ws);
        hipLaunchKernelGGL(nnue_mono, dim3(B), dim3(256), 0, stream,
                           pp, kp, W, ib, w1, b1, w2, b2, ow, ws);
        hipLaunchKernelGGL(nnue_finalize, dim3(1), dim3(1), 0, stream, ws, ob, out);
    }
}

// Round 7
// 164.426 us; speedup vs baseline: 3.4223x; 1.0102x over previous
//
#include <hip/hip_runtime.h>
#include <stdint.h>

#define NDIM  256   // accumulator width
#define NFEAT 640   // piece features per sample
#define NROWS 641   // 640 features + 1 king bias row
#define SG    8     // slots processed together per block
#define MAXG  16    // max slot-groups per king (covers 128 slots/king)
#define MAXRPB 320  // max rows per block (rp=2 case)

typedef unsigned short ushort4v __attribute__((ext_vector_type(4)));
typedef unsigned short ushort8v __attribute__((ext_vector_type(8)));

// ============================ bucket + detect ============================
// ws[0]=scalar sum, ws[1]=raw-int16 weights flag, ws[2]=raw-bool pp flag, ws[3]=done counter
__global__ void nnue_bucket(const int* __restrict__ kp, const int* __restrict__ W32,
                            const int* __restrict__ pp32, int nslots,
                            int* __restrict__ ws,
                            int* __restrict__ king_start, int* __restrict__ slot_list,
                            int* __restrict__ slot_pos)
{
    __shared__ int cnt[64];
    __shared__ int off[64];
    const int t = threadIdx.x;
    if (t < 64) cnt[t] = 0;
    if (t == 0) {
        int raww = 0, rawpp = 0;
        for (int i = 0; i < 16; ++i) {
            const int v = W32[i];                     // int32 layout => |v| <= 32767
            if (v > 32767 || v < -32768) raww = 1;    // packed int16 pairs look huge
            const int u = pp32[i];                    // int32 layout => {0,1}
            if (u != 0 && u != 1) rawpp = 1;          // packed bool bytes exceed 1
        }
        ws[0] = 0; ws[1] = raww; ws[2] = rawpp; ws[3] = 0;
    }
    __syncthreads();
    for (int s = t; s < nslots; s += 256) atomicAdd(&cnt[kp[s]], 1);
    __syncthreads();
    if (t == 0) {
        int run = 0;
        for (int k = 0; k < 64; ++k) { off[k] = run; king_start[k] = run; run += cnt[k]; }
        king_start[64] = run;
    }
    __syncthreads();
    for (int s = t; s < nslots; s += 256) {
        const int k = kp[s];
        const int pos = atomicAdd(&off[k], 1);
        slot_list[pos] = s;       // s = 2*sample + side
        slot_pos[s] = pos;
    }
}

// ============================ king-major gather (R3 measured-best, unchanged) ============================
struct GatherLds {
    int samp[SG];
    unsigned mask[MAXRPB];            // per-row activity bits for the SG slots
    unsigned red[4][SG][NDIM / 2];    // packed u16 pairs, per-wave partials (16 KB)
};

template<bool RAWW, bool RAWPP>
__device__ __forceinline__ void gather_body(
    const void* __restrict__ ppv, const void* __restrict__ Wv,
    const int* __restrict__ king_start, const int* __restrict__ slot_list,
    unsigned short* __restrict__ partial, int nslots, int rp, GatherLds& sh)
{
    const int bid = blockIdx.x;
    const int k = bid & 63;            // king; bid%8 == k%8 -> XCD pinning
    const int rest = bid >> 6;
    const int p = rest & (rp - 1);     // row part (rp is 2 or 4)
    const int gi = rest / rp;          // slot group
    const int t = threadIdx.x, l = t & 63, g = t >> 6;

    const int s0 = king_start[k], s1 = king_start[k + 1];
    const int base = s0 + gi * SG;
    if (base >= s1) return;            // uniform across block
    const int ns = min(SG, s1 - base);
    const unsigned emask = (ns >= 32) ? 0xFFFFFFFFu : ((1u << ns) - 1u);
    const int rpb = NFEAT / rp;        // rows this block handles
    const int r0 = p * rpb;

    if (t < SG) sh.samp[t] = slot_list[base + min(t, ns - 1)] >> 1;
    __syncthreads();

    // ---- per-row activity masks for rows [r0, r0+rpb) ----
    for (int r = t; r < rpb; r += 256) {
        unsigned mm = 0;
        #pragma unroll
        for (int i = 0; i < SG; ++i) {
            const int s = sh.samp[i];
            int v;
            if (RAWPP) v = ((const uint8_t*)ppv)[(size_t)s * NFEAT + r0 + r];
            else       v = ((const int*)ppv)[(size_t)s * NFEAT + r0 + r];
            mm |= (v != 0 ? 1u : 0u) << i;
        }
        sh.mask[r] = mm & emask;
    }
    __syncthreads();

    // ---- row loop: one row load, packed-u16 adds into active slots (mod 2^16 exact) ----
    ushort4v acc[SG];
    #pragma unroll
    for (int i = 0; i < SG; ++i) acc[i] = (ushort4v)0;

    const char* Wk = (const char*)Wv + (size_t)k * NROWS * NDIM * (RAWW ? 2 : 4);
    const int rows_per_wave = rpb / 4;
    const int lbeg = g * rows_per_wave;

    #pragma unroll 2
    for (int rr = 0; rr < rows_per_wave; ++rr) {
        const int lr = lbeg + rr;                    // local row index in [0, rpb)
        unsigned mm = sh.mask[lr];
        mm = __builtin_amdgcn_readfirstlane(mm);     // wave-uniform -> scalar branches
        ushort4v w;
        if (RAWW) {
            w = *(const ushort4v*)(Wk + (size_t)(r0 + lr) * 512 + (size_t)l * 8);
        } else {
            const int4 u = *(const int4*)(Wk + (size_t)(r0 + lr) * 1024 + (size_t)l * 16);
            w.x = (unsigned short)u.x; w.y = (unsigned short)u.y;
            w.z = (unsigned short)u.z; w.w = (unsigned short)u.w;
        }
        #pragma unroll
        for (int i = 0; i < SG; ++i)
            if (mm & (1u << i)) acc[i] += w;         // 2x v_pk_add_u16 behind scalar branch
    }

    // ---- cross-wave reduce in LDS, write u16 partials ----
    #pragma unroll
    for (int i = 0; i < SG; ++i)
        *(ushort4v*)&sh.red[g][i][2 * l] = acc[i];
    __syncthreads();

    const int i = t >> 5;              // slot 0..7
    const int j4 = (t & 31) * 4;       // uint index within slot (128 uints = 256 u16)
    if (i < ns) {
        ushort8v s = *(const ushort8v*)&sh.red[0][i][j4];
        #pragma unroll
        for (int g2 = 1; g2 < 4; ++g2) s += *(const ushort8v*)&sh.red[g2][i][j4];
        *(ushort8v*)&partial[((size_t)p * nslots + base + i) * NDIM + (size_t)(t & 31) * 8] = s;
    }
}

__global__ __launch_bounds__(256, 6) void nnue_gather(
    const void* __restrict__ pp, const void* __restrict__ W,
    const int* __restrict__ ws, const int* __restrict__ king_start,
    const int* __restrict__ slot_list, unsigned short* __restrict__ partial,
    int nslots, int rp)
{
    __shared__ GatherLds sh;
    const int raww = ws[1], rawpp = ws[2];
    if (raww) {
        if (rawpp) gather_body<true,  true >(pp, W, king_start, slot_list, partial, nslots, rp, sh);
        else       gather_body<true,  false>(pp, W, king_start, slot_list, partial, nslots, rp, sh);
    } else {
        if (rawpp) gather_body<false, true >(pp, W, king_start, slot_list, partial, nslots, rp, sh);
        else       gather_body<false, false>(pp, W, king_start, slot_list, partial, nslots, rp, sh);
    }
}

// ============================ combine + FC layers + fused finalize ============================
struct CombineLds {
    alignas(16) int8_t x[NDIM];
    int fc[256];
    alignas(4) int8_t x2[32];
};

template<bool RAWW>
__device__ __forceinline__ void combine_body(
    const unsigned short* __restrict__ partial, const int* __restrict__ slot_pos,
    const int* __restrict__ kp, const void* __restrict__ Wv,
    const void* __restrict__ ibv,
    const void* __restrict__ w1v, const int* __restrict__ b1,
    const void* __restrict__ w2v, const int* __restrict__ b2,
    const void* __restrict__ owv, const int* __restrict__ ob,
    int* __restrict__ ws, int* __restrict__ out, int nslots, int rp,
    CombineLds& sh)
{
    const int b = blockIdx.x;
    const int t = threadIdx.x;

    const int pos0 = slot_pos[2 * b + 0];
    const int pos1 = slot_pos[2 * b + 1];
    const int k0 = kp[2 * b + 0];
    const int k1 = kp[2 * b + 1];
    {
        unsigned tot = 0;  // u16 arithmetic carried in u32; truncate at end
        for (int pi = 0; pi < rp; ++pi) {
            tot += partial[((size_t)pi * nslots + pos0) * NDIM + t];
            tot += partial[((size_t)pi * nslots + pos1) * NDIM + t];
        }
        if (RAWW) {
            const uint16_t* Wq = (const uint16_t*)Wv;
            tot += Wq[((size_t)k0 * NROWS + NFEAT) * NDIM + t];
            tot += Wq[((size_t)k1 * NROWS + NFEAT) * NDIM + t];
            tot += ((const uint16_t*)ibv)[t];
        } else {
            const int* Wq = (const int*)Wv;
            tot += (unsigned)Wq[((size_t)k0 * NROWS + NFEAT) * NDIM + t];
            tot += (unsigned)Wq[((size_t)k1 * NROWS + NFEAT) * NDIM + t];
            tot += (unsigned)((const int*)ibv)[t];
        }
        int v = (int)(int16_t)(uint16_t)tot;   // int16 wraparound semantics
        v = v < 0 ? 0 : (v > 127 ? 127 : v);
        sh.x[t] = (int8_t)v;
    }
    __syncthreads();

    // ---- FC1: 32 outputs over concat([x,x]) = fold the two 256-halves of w1 ----
    {
        const int o = t >> 3, part = t & 7;
        int y = 0;
        const uint32_t* xw = (const uint32_t*)sh.x;
        if (RAWW) {
            const uint32_t* w1r = (const uint32_t*)((const char*)w1v + o * 512);
            #pragma unroll
            for (int i = 0; i < 8; ++i) {
                const int wi = part * 8 + i;
                const uint32_t xv = xw[wi];
                const uint32_t wa = w1r[wi];
                const uint32_t wb = w1r[64 + wi];
                #pragma unroll
                for (int jj = 0; jj < 4; ++jj) {
                    const int xj  = (int)((xv >> (8 * jj)) & 0xFFu);
                    const int waj = (int)(int8_t)(uint8_t)(wa >> (8 * jj));
                    const int wbj = (int)(int8_t)(uint8_t)(wb >> (8 * jj));
                    y += xj * (waj + wbj);
                }
            }
        } else {
            const int* w1r = (const int*)w1v + o * 512;
            #pragma unroll
            for (int i = 0; i < 8; ++i) {
                const int wi = part * 8 + i;
                const uint32_t xv = xw[wi];
                #pragma unroll
                for (int jj = 0; jj < 4; ++jj) {
                    const int xj = (int)((xv >> (8 * jj)) & 0xFFu);
                    y += xj * (w1r[wi * 4 + jj] + w1r[256 + wi * 4 + jj]);
                }
            }
        }
        sh.fc[t] = y;
    }
    __syncthreads();

    if (t < 32) {
        int y = b1[t];
        #pragma unroll
        for (int pq = 0; pq < 8; ++pq) y += sh.fc[t * 8 + pq];
        y >>= 6;                                  // floor_divide(y, 64)
        y = y < 0 ? 0 : (y > 127 ? 127 : y);
        sh.x2[t] = (int8_t)y;
    }
    __syncthreads();

    // ---- FC2 + output dot + block reduction + fused finalize ----
    if (t < 32) {
        int y = b2[t];
        const uint32_t* x2w = (const uint32_t*)sh.x2;
        if (RAWW) {
            const uint32_t* w2r = (const uint32_t*)((const char*)w2v + t * 32);
            #pragma unroll
            for (int i = 0; i < 8; ++i) {
                const uint32_t xv = x2w[i];
                const uint32_t wv = w2r[i];
                #pragma unroll
                for (int jj = 0; jj < 4; ++jj)
                    y += (int)((xv >> (8 * jj)) & 0xFFu) * (int)(int8_t)(uint8_t)(wv >> (8 * jj));
            }
        } else {
            const int* w2r = (const int*)w2v + t * 32;
            #pragma unroll
            for (int i = 0; i < 8; ++i) {
                const uint32_t xv = x2w[i];
                #pragma unroll
                for (int jj = 0; jj < 4; ++jj)
                    y += (int)((xv >> (8 * jj)) & 0xFFu) * w2r[i * 4 + jj];
            }
        }
        y >>= 6;
        y = y < 0 ? 0 : (y > 127 ? 127 : y);
        const int owx = RAWW ? (int)((const int8_t*)owv)[t] : ((const int*)owv)[t];
        int pr = y * owx;
        #pragma unroll
        for (int off = 16; off > 0; off >>= 1) pr += __shfl_down(pr, off, 32);
        if (t == 0) {
            atomicAdd(ws, pr);
            __threadfence();                       // my add visible before signaling done
            const int prev = atomicAdd(ws + 3, 1);
            if (prev == (int)gridDim.x - 1) {      // last block finalizes
                __threadfence();
                const int s = atomicAdd(ws, 0);    // atomic read of the total
                out[0] = (s + ob[0]) >> 4;         // floor_divide(s, 16)
            }
        }
    }
}

__global__ __launch_bounds__(256) void nnue_combine(
    const unsigned short* __restrict__ partial, const int* __restrict__ slot_pos,
    const int* __restrict__ kp, const void* __restrict__ W,
    const void* __restrict__ ib,
    const void* __restrict__ w1, const int* __restrict__ b1,
    const void* __restrict__ w2, const int* __restrict__ b2,
    const void* __restrict__ ow, const int* __restrict__ ob,
    int* __restrict__ ws, int* __restrict__ out, int nslots, int rp)
{
    __shared__ CombineLds sh;
    if (ws[1]) combine_body<true >(partial, slot_pos, kp, W, ib, w1, b1, w2, b2, ow, ob, ws, out, nslots, rp, sh);
    else       combine_body<false>(partial, slot_pos, kp, W, ib, w1, b1, w2, b2, ow, ob, ws, out, nslots, rp, sh);
}

// ============================ fallback (round-1 monolithic, proven) ============================
struct SharedBuf {
    uint8_t pp[NFEAT];
    int     acc[4][NDIM];
    alignas(16) int8_t x[NDIM];
    int     fc[256];
    alignas(4) int8_t x2[32];
    int     list[4][160];
};

__global__ void detect_layout(const int* __restrict__ W32, const int* __restrict__ pp32,
                              int* __restrict__ ws) {
    int raww = 0, rawpp = 0;
    for (int i = 0; i < 16; ++i) {
        const int v = W32[i];
        if (v > 32767 || v < -32768) raww = 1;
        const int u = pp32[i];
        if (u != 0 && u != 1) rawpp = 1;
    }
    ws[0] = 0; ws[1] = raww; ws[2] = rawpp;
}

template<bool RAWW, bool RAWPP>
__device__ __forceinline__ void mono_body(
    const void* __restrict__ ppv, const int* __restrict__ kp,
    const void* __restrict__ Wv,  const void* __restrict__ ibv,
    const void* __restrict__ w1v, const int* __restrict__ b1,
    const void* __restrict__ w2v, const int* __restrict__ b2,
    const void* __restrict__ owv, int* __restrict__ ws, SharedBuf& sh)
{
    const int b = blockIdx.x;
    const int t = threadIdx.x;
    const int l = t & 63;
    const int g = t >> 6;

    if (RAWPP) {
        const uint32_t* src = (const uint32_t*)((const uint8_t*)ppv + (size_t)b * NFEAT);
        if (t < NFEAT / 4) ((uint32_t*)sh.pp)[t] = src[t];
    } else {
        const int* src = (const int*)ppv + (size_t)b * NFEAT;
        for (int i = t; i < NFEAT; i += 256) sh.pp[i] = (uint8_t)(src[i] != 0);
    }
    __syncthreads();

    const int base = g * 160;
    int cnt = 0;
    for (int c = 0; c < 160; c += 64) {
        const int idx = c + l;
        const bool flag = (idx < 160) && (sh.pp[base + idx] != 0);
        const unsigned long long mmask = __ballot(flag);
        const int pos = cnt + (int)__popcll(mmask & ((1ull << l) - 1ull));
        if (flag) sh.list[g][pos] = base + idx;
        cnt += (int)__popcll(mmask);
    }

    const int k0 = kp[b * 2 + 0];
    const int k1 = kp[b * 2 + 1];
    int a0 = 0, a1 = 0, a2 = 0, a3 = 0, a4 = 0, a5 = 0, a6 = 0, a7 = 0;

    if (RAWW) {
        const char* W0 = (const char*)Wv + (size_t)k0 * (NROWS * NDIM * 2);
        const char* W1 = (const char*)Wv + (size_t)k1 * (NROWS * NDIM * 2);
        const int lo = l * 8;
        auto step = [&](int f) {
            const uint2 u0 = *(const uint2*)(W0 + f * 512 + lo);
            const uint2 u1 = *(const uint2*)(W1 + f * 512 + lo);
            a0 += (int)(u0.x & 0xFFFFu); a1 += (int)(u0.x >> 16);
            a2 += (int)(u0.y & 0xFFFFu); a3 += (int)(u0.y >> 16);
            a4 += (int)(u1.x & 0xFFFFu); a5 += (int)(u1.x >> 16);
            a6 += (int)(u1.y & 0xFFFFu); a7 += (int)(u1.y >> 16);
        };
        int j = 0;
        for (; j + 4 <= cnt; j += 4) {
            const int f0 = sh.list[g][j], f1 = sh.list[g][j + 1];
            const int f2 = sh.list[g][j + 2], f3 = sh.list[g][j + 3];
            step(f0); step(f1); step(f2); step(f3);
        }
        for (; j < cnt; ++j) step(sh.list[g][j]);
    } else {
        const char* W0 = (const char*)Wv + (size_t)k0 * (NROWS * NDIM * 4);
        const char* W1 = (const char*)Wv + (size_t)k1 * (NROWS * NDIM * 4);
        const int lo = l * 16;
        auto step = [&](int f) {
            const int4 u0 = *(const int4*)(W0 + f * 1024 + lo);
            const int4 u1 = *(const int4*)(W1 + f * 1024 + lo);
            a0 += u0.x; a1 += u0.y; a2 += u0.z; a3 += u0.w;
            a4 += u1.x; a5 += u1.y; a6 += u1.z; a7 += u1.w;
        };
        int j = 0;
        for (; j + 4 <= cnt; j += 4) {
            const int f0 = sh.list[g][j], f1 = sh.list[g][j + 1];
            const int f2 = sh.list[g][j + 2], f3 = sh.list[g][j + 3];
            step(f0); step(f1); step(f2); step(f3);
        }
        for (; j < cnt; ++j) step(sh.list[g][j]);
    }

    sh.acc[g][4 * l + 0] = a0 + a4;
    sh.acc[g][4 * l + 1] = a1 + a5;
    sh.acc[g][4 * l + 2] = a2 + a6;
    sh.acc[g][4 * l + 3] = a3 + a7;
    __syncthreads();

    {
        const int d = t;
        int tot = sh.acc[0][d] + sh.acc[1][d] + sh.acc[2][d] + sh.acc[3][d];
        int kb0, kb1, ibx;
        if (RAWW) {
            const int16_t* Wq = (const int16_t*)Wv;
            kb0 = Wq[((size_t)k0 * NROWS + NFEAT) * NDIM + d];
            kb1 = Wq[((size_t)k1 * NROWS + NFEAT) * NDIM + d];
            ibx = ((const int16_t*)ibv)[d];
        } else {
            const int* Wq = (const int*)Wv;
            kb0 = Wq[((size_t)k0 * NROWS + NFEAT) * NDIM + d];
            kb1 = Wq[((size_t)k1 * NROWS + NFEAT) * NDIM + d];
            ibx = ((const int*)ibv)[d];
        }
        tot += kb0 + kb1 + ibx;
        int v = (int)(int16_t)(uint16_t)(uint32_t)tot;
        v = v < 0 ? 0 : (v > 127 ? 127 : v);
        sh.x[d] = (int8_t)v;
    }
    __syncthreads();

    {
        const int o = t >> 3, part = t & 7;
        int y = 0;
        const uint32_t* xw = (const uint32_t*)sh.x;
        if (RAWW) {
            const uint32_t* w1r = (const uint32_t*)((const char*)w1v + o * 512);
            #pragma unroll
            for (int i = 0; i < 8; ++i) {
                const int wi = part * 8 + i;
                const uint32_t xv = xw[wi];
                const uint32_t wa = w1r[wi];
                const uint32_t wb = w1r[64 + wi];
                #pragma unroll
                for (int jj = 0; jj < 4; ++jj) {
                    const int xj  = (int)((xv >> (8 * jj)) & 0xFFu);
                    const int waj = (int)(int8_t)(uint8_t)(wa >> (8 * jj));
                    const int wbj = (int)(int8_t)(uint8_t)(wb >> (8 * jj));
                    y += xj * (waj + wbj);
                }
            }
        } else {
            const int* w1r = (const int*)w1v + o * 512;
            #pragma unroll
            for (int i = 0; i < 8; ++i) {
                const int wi = part * 8 + i;
                const uint32_t xv = xw[wi];
                #pragma unroll
                for (int jj = 0; jj < 4; ++jj) {
                    const int xj = (int)((xv >> (8 * jj)) & 0xFFu);
                    y += xj * (w1r[wi * 4 + jj] + w1r[256 + wi * 4 + jj]);
                }
            }
        }
        sh.fc[t] = y;
    }
    __syncthreads();

    if (t < 32) {
        int y = b1[t];
        #pragma unroll
        for (int pq = 0; pq < 8; ++pq) y += sh.fc[t * 8 + pq];
        y >>= 6;
        y = y < 0 ? 0 : (y > 127 ? 127 : y);
        sh.x2[t] = (int8_t)y;
    }
    __syncthreads();

    if (t < 32) {
        int y = b2[t];
        const uint32_t* x2w = (const uint32_t*)sh.x2;
        if (RAWW) {
            const uint32_t* w2r = (const uint32_t*)((const char*)w2v + t * 32);
            #pragma unroll
            for (int i = 0; i < 8; ++i) {
                const uint32_t xv = x2w[i];
                const uint32_t wv = w2r[i];
                #pragma unroll
                for (int jj = 0; jj < 4; ++jj)
                    y += (int)((xv >> (8 * jj)) & 0xFFu) * (int)(int8_t)(uint8_t)(wv >> (8 * jj));
            }
        } else {
            const int* w2r = (const int*)w2v + t * 32;
            #pragma unroll
            for (int i = 0; i < 8; ++i) {
                const uint32_t xv = x2w[i];
                #pragma unroll
                for (int jj = 0; jj < 4; ++jj)
                    y += (int)((xv >> (8 * jj)) & 0xFFu) * w2r[i * 4 + jj];
            }
        }
        y >>= 6;
        y = y < 0 ? 0 : (y > 127 ? 127 : y);
        const int owx = RAWW ? (int)((const int8_t*)owv)[t] : ((const int*)owv)[t];
        int pr = y * owx;
        #pragma unroll
        for (int off = 16; off > 0; off >>= 1) pr += __shfl_down(pr, off, 32);
        if (t == 0) atomicAdd(ws, pr);
    }
}

__global__ __launch_bounds__(256, 4) void nnue_mono(
    const void* __restrict__ pp, const int* __restrict__ kp,
    const void* __restrict__ W,  const void* __restrict__ ib,
    const void* __restrict__ w1, const int* __restrict__ b1,
    const void* __restrict__ w2, const int* __restrict__ b2,
    const void* __restrict__ ow, int* __restrict__ ws)
{
    __shared__ SharedBuf sh;
    const int raww = ws[1], rawpp = ws[2];
    if (raww) {
        if (rawpp) mono_body<true,  true >(pp, kp, W, ib, w1, b1, w2, b2, ow, ws, sh);
        else       mono_body<true,  false>(pp, kp, W, ib, w1, b1, w2, b2, ow, ws, sh);
    } else {
        if (rawpp) mono_body<false, true >(pp, kp, W, ib, w1, b1, w2, b2, ow, ws, sh);
        else       mono_body<false, false>(pp, kp, W, ib, w1, b1, w2, b2, ow, ws, sh);
    }
}

__global__ void nnue_finalize(const int* __restrict__ ws, const int* __restrict__ ob,
                              int* __restrict__ out) {
    out[0] = (ws[0] + ob[0]) >> 4;  // floor_divide(s, 16)
}

// ============================ host launch ============================
extern "C" void kernel_launch(void* const* d_in, const int* in_sizes, int n_in,
                              void* d_out, int out_size, void* d_ws, size_t ws_size,
                              hipStream_t stream)
{
    const void* pp = d_in[0];
    const int*  kp = (const int*)d_in[1];
    const void* W  = d_in[2];
    const void* ib = d_in[3];
    const void* w1 = d_in[4];
    const int*  b1 = (const int*)d_in[5];
    const void* w2 = d_in[6];
    const int*  b2 = (const int*)d_in[7];
    const void* ow = d_in[8];
    const int*  ob = (const int*)d_in[9];
    int* ws  = (int*)d_ws;
    int* out = (int*)d_out;

    const int B = in_sizes[1] / 2;   // king_positions is (B, 2)
    const int nslots = 2 * B;

    // ws layout (int offsets): [0..3] sum/flags/done, [16..80] king_start,
    // [96..96+nslots) slot_list, [..+nslots) slot_pos, u16 partial (256-int aligned)
    const size_t off_ks = 16;
    const size_t off_sl = 96;
    const size_t off_sp = off_sl + (size_t)nslots;
    const size_t off_pb = ((off_sp + (size_t)nslots + 255) / 256) * 256;
    // partial: rp * nslots * NDIM ushorts = rp * nslots * 128 ints
    const size_t need4 = (off_pb + (size_t)4 * nslots * (NDIM / 2)) * 4;
    const size_t need2 = (off_pb + (size_t)2 * nslots * (NDIM / 2)) * 4;

    int rp = 0;
    if (ws_size >= need4) rp = 4;
    else if (ws_size >= need2) rp = 2;

    if (rp) {
        int* king_start = ws + off_ks;
        int* slot_list  = ws + off_sl;
        int* slot_pos   = ws + off_sp;
        unsigned short* partial = (unsigned short*)(ws + off_pb);

        hipLaunchKernelGGL(nnue_bucket, dim3(1), dim3(256), 0, stream,
                           kp, (const int*)W, (const int*)pp, nslots,
                           ws, king_start, slot_list, slot_pos);
        hipLaunchKernelGGL(nnue_gather, dim3(64 * MAXG * rp), dim3(256), 0, stream,
                           pp, W, ws, king_start, slot_list, partial, nslots, rp);
        hipLaunchKernelGGL(nnue_combine, dim3(B), dim3(256), 0, stream,
                           partial, slot_pos, kp, W, ib, w1, b1, w2, b2, ow, ob,
                           ws, out, nslots, rp);
    } else {
        // fallback: round-1 monolithic path (proven)
        hipLaunchKernelGGL(detect_layout, dim3(1), dim3(1), 0, stream,
                           (const int*)W, (const int*)pp, ws);
        hipLaunchKernelGGL(nnue_mono, dim3(B), dim3(256), 0, stream,
                           pp, kp, W, ib, w1, b1, w2, b2, ow, ws);
        hipLaunchKernelGGL(nnue_finalize, dim3(1), dim3(1), 0, stream, ws, ob, out);
    }
}